// Round 3
// baseline (4657.732 us; speedup 1.0000x reference)
//
#include <hip/hip_runtime.h>
#include <hip/hip_bf16.h>
#include <math.h>

// ---------------------------------------------------------------------------
// IMPGNN on MI355X. fp32 compute, bf16 edge intermediates (2%-of-absmax tol).
// R3 changes vs R2:
//   - pagerank: 100 launches -> 1 persistent kernel w/ manual grid barrier
//     (98 blocks x 512 thr, co-resident by construction; cumulative-counter
//     barrier, __threadfence release/acquire for cross-XCD visibility)
//   - line-graph path: if ws_size permits (+102 MB), atomic-free variant:
//     v[e]=sc(u[e]+sum u[e']) bf16, then node-CSR gather -> g0 (no fp32
//     atomics, no 400 MB write-through). Fallback: R2 scatter path.
// ---------------------------------------------------------------------------

#define POOL_BLOCKS 400
#define SCAN_NB 256
#define PR_THREADS 512

typedef unsigned short ushort_t;
typedef unsigned int uint_t;

__device__ __forceinline__ float eluf(float x) { return x > 0.f ? x : expm1f(x); }
__device__ __forceinline__ float bf2f(ushort_t v) {
    return __uint_as_float(((unsigned int)v) << 16);
}
__device__ __forceinline__ ushort_t f2bf(float f) {
    unsigned int u = __float_as_uint(f);
    unsigned int lsb = (u >> 16) & 1u;
    u += 0x7fffu + lsb;           // round-to-nearest-even
    return (ushort_t)(u >> 16);
}
__device__ __forceinline__ float bflo(uint_t v) { return __uint_as_float(v << 16); }
__device__ __forceinline__ float bfhi(uint_t v) { return __uint_as_float(v & 0xffff0000u); }
__device__ __forceinline__ uint_t packbf(float a, float b) {
    return (uint_t)f2bf(a) | ((uint_t)f2bf(b) << 16);
}

// ---------------- CSR build ----------------
__global__ void k_count(const int* __restrict__ a, const int* __restrict__ b,
                        int E, int* __restrict__ deg) {
    int e = blockIdx.x * blockDim.x + threadIdx.x;
    if (e < E) { atomicAdd(&deg[a[e]], 1); atomicAdd(&deg[b[e]], 1); }
}

__global__ void k_scan1(const int* __restrict__ deg, int n, int C, int* __restrict__ bsum) {
    __shared__ int red[256];
    int b = blockIdx.x, tid = threadIdx.x;
    int base = b * C, end = min(base + C, n);
    int s = 0;
    for (int i = base + tid; i < end; i += 256) s += deg[i];
    red[tid] = s;
    __syncthreads();
    for (int off = 128; off > 0; off >>= 1) {
        if (tid < off) red[tid] += red[tid + off];
        __syncthreads();
    }
    if (tid == 0) bsum[b] = red[0];
}

__global__ void k_scan2(int* __restrict__ bsum, int NB, int* __restrict__ total_out) {
    __shared__ int s[256];
    int tid = threadIdx.x;
    int v = (tid < NB) ? bsum[tid] : 0;
    s[tid] = v;
    __syncthreads();
    for (int off = 1; off < 256; off <<= 1) {
        int w = (tid >= off) ? s[tid - off] : 0;
        __syncthreads();
        s[tid] += w;
        __syncthreads();
    }
    if (tid < NB) bsum[tid] = s[tid] - v;
    if (tid == 255) *total_out = s[255];
}

__global__ void k_scan3(const int* __restrict__ deg, const int* __restrict__ boff,
                        int n, int C, int* __restrict__ ptr, int* __restrict__ cur) {
    __shared__ int s[256];
    __shared__ int carry;
    int b = blockIdx.x, tid = threadIdx.x;
    int base = b * C, end = min(base + C, n);
    if (tid == 0) carry = boff[b];
    __syncthreads();
    for (int t = base; t < end; t += 256) {
        int i = t + tid;
        int v = (i < end) ? deg[i] : 0;
        s[tid] = v;
        __syncthreads();
        for (int off = 1; off < 256; off <<= 1) {
            int w = (tid >= off) ? s[tid - off] : 0;
            __syncthreads();
            s[tid] += w;
            __syncthreads();
        }
        int p = carry + s[tid] - v;
        if (i < end) { ptr[i] = p; cur[i] = p; }
        __syncthreads();
        if (tid == 0) carry += s[255];
        __syncthreads();
    }
}

__global__ void k_fill(const int* __restrict__ a, const int* __restrict__ b, int E,
                       int* __restrict__ cur, int* __restrict__ nbr,
                       int* __restrict__ eid, int cap) {
    int e = blockIdx.x * blockDim.x + threadIdx.x;
    if (e < E) {
        int s = a[e], d = b[e];
        int p = atomicAdd(&cur[s], 1);
        if (p < cap) { nbr[p] = d; if (eid) eid[p] = e; }
        int q = atomicAdd(&cur[d], 1);
        if (q < cap) { nbr[q] = s; if (eid) eid[q] = e; }
    }
}

// ---------------- encoders ----------------
__global__ void k_encoder(const int* __restrict__ x, const float* __restrict__ metafeat,
                          const float* __restrict__ atom_emb, const float* __restrict__ meta_W,
                          const float* __restrict__ meta_b, float* __restrict__ nf0,
                          float* __restrict__ mf0, int N) {
    __shared__ float W[16 * 128];
    __shared__ float bsh[128];
    for (int i = threadIdx.x; i < 16 * 128; i += blockDim.x) W[i] = meta_W[i];
    if (threadIdx.x < 128) bsh[threadIdx.x] = meta_b[threadIdx.x];
    __syncthreads();
    int idx = blockIdx.x * blockDim.x + threadIdx.x;
    if (idx < N * 128) {
        int i = idx >> 7, j = idx & 127;
        nf0[idx] = atom_emb[x[i] * 128 + j];
        const float* mrow = metafeat + i * 16;
        float acc = bsh[j];
#pragma unroll
        for (int k = 0; k < 16; k++) acc = fmaf(mrow[k], W[k * 128 + j], acc);
        mf0[idx] = acc;
    }
}

__global__ void k_gate_node(const int* __restrict__ ptr, const int* __restrict__ eid_arr,
                            const int* __restrict__ edge_attr, const float* __restrict__ bond_emb,
                            float* __restrict__ gate, int N) {
    __shared__ float bond[8 * 128];
    for (int i = threadIdx.x; i < 8 * 128; i += blockDim.x) bond[i] = bond_emb[i];
    __syncthreads();
    int j = threadIdx.x & 127, li = threadIdx.x >> 7;
    int node = blockIdx.x * 2 + li;
    if (node >= N) return;
    int p0 = ptr[node], p1 = ptr[node + 1];
    float g = 0.f;
    for (int p = p0; p < p1; p++) g += bond[edge_attr[eid_arr[p]] * 128 + j];
    gate[(size_t)node * 128 + j] = g;
}

// ---------------- GEMM ----------------
template <int GATED, int EPI>
__global__ __launch_bounds__(256, 4) void k_gemm(
    const float* __restrict__ X, const float* __restrict__ G,
    const float* __restrict__ W, const float* __restrict__ bias,
    const int* __restrict__ deg, float* __restrict__ out, int M) {
    __shared__ float As[128][33];
    __shared__ float Bs[32][128];
    int tid = threadIdx.x;
    int tx = tid & 15, ty = tid >> 4;
    int row0 = blockIdx.x * 128;

    float acc[8][8];
#pragma unroll
    for (int i = 0; i < 8; i++)
#pragma unroll
        for (int j = 0; j < 8; j++) acc[i][j] = 0.f;

    for (int h = 0; h < 4; h++) {
#pragma unroll
        for (int p = 0; p < 4; p++) {
            int idx = p * 256 + tid;
            int kk = idx >> 5, cg = idx & 31;
            float4 w = *reinterpret_cast<const float4*>(W + (h * 32 + kk) * 128 + cg * 4);
            *reinterpret_cast<float4*>(&Bs[kk][cg * 4]) = w;
        }
        int kg = tid & 7, rr = tid >> 3;
#pragma unroll
        for (int p = 0; p < 4; p++) {
            int r = p * 32 + rr;
            int grow = row0 + r;
            int k = h * 32 + kg * 4;
            float4 av;
            if (grow < M) {
                float4 xv = *reinterpret_cast<const float4*>(X + (size_t)grow * 128 + k);
                if (GATED) {
                    float4 gv = *reinterpret_cast<const float4*>(G + (size_t)grow * 128 + k);
                    av.x = eluf(xv.x * gv.x); av.y = eluf(xv.y * gv.y);
                    av.z = eluf(xv.z * gv.z); av.w = eluf(xv.w * gv.w);
                } else av = xv;
            } else av = make_float4(0.f, 0.f, 0.f, 0.f);
            As[r][kg * 4 + 0] = av.x; As[r][kg * 4 + 1] = av.y;
            As[r][kg * 4 + 2] = av.z; As[r][kg * 4 + 3] = av.w;
        }
        __syncthreads();
#pragma unroll 8
        for (int k = 0; k < 32; k++) {
            float a[8], b[8];
#pragma unroll
            for (int i = 0; i < 8; i++) a[i] = As[ty * 8 + i][k];
            float4 b0 = *reinterpret_cast<const float4*>(&Bs[k][tx * 4]);
            float4 b1 = *reinterpret_cast<const float4*>(&Bs[k][64 + tx * 4]);
            b[0] = b0.x; b[1] = b0.y; b[2] = b0.z; b[3] = b0.w;
            b[4] = b1.x; b[5] = b1.y; b[6] = b1.z; b[7] = b1.w;
#pragma unroll
            for (int i = 0; i < 8; i++)
#pragma unroll
                for (int j = 0; j < 8; j++) acc[i][j] = fmaf(a[i], b[j], acc[i][j]);
        }
        __syncthreads();
    }
#pragma unroll
    for (int i = 0; i < 8; i++) {
        int r = row0 + ty * 8 + i;
        if (r < M) {
            float4 o0, o1;
            if (EPI == 0) {
                float sc = rsqrtf((float)deg[r] + 1.0f);
                o0 = make_float4(acc[i][0] * sc, acc[i][1] * sc, acc[i][2] * sc, acc[i][3] * sc);
                o1 = make_float4(acc[i][4] * sc, acc[i][5] * sc, acc[i][6] * sc, acc[i][7] * sc);
            } else {
                float dg = (float)deg[r];
                float4 ba = *reinterpret_cast<const float4*>(bias + tx * 4);
                float4 bb = *reinterpret_cast<const float4*>(bias + 64 + tx * 4);
                o0 = make_float4(acc[i][0] + dg * ba.x, acc[i][1] + dg * ba.y,
                                 acc[i][2] + dg * ba.z, acc[i][3] + dg * ba.w);
                o1 = make_float4(acc[i][4] + dg * bb.x, acc[i][5] + dg * bb.y,
                                 acc[i][6] + dg * bb.z, acc[i][7] + dg * bb.w);
            }
            *reinterpret_cast<float4*>(out + (size_t)r * 128 + tx * 4) = o0;
            *reinterpret_cast<float4*>(out + (size_t)r * 128 + 64 + tx * 4) = o1;
        }
    }
}

// ---------------- node-graph aggregations ----------------
__global__ void k_agg_dual(const int* __restrict__ ptr, const int* __restrict__ nbr,
                           const float* __restrict__ m0, const float* __restrict__ m1,
                           const float* __restrict__ b0, const float* __restrict__ b1,
                           const int* __restrict__ deg, float* __restrict__ h0,
                           float* __restrict__ h1, int n) {
    int j = threadIdx.x & 127, li = threadIdx.x >> 7;
    int node = blockIdx.x * 2 + li;
    if (node >= n) return;
    int p0 = ptr[node], p1 = ptr[node + 1];
    size_t idx = (size_t)node * 128 + j;
    float a0 = m0[idx], a1 = m1[idx];
    for (int p = p0; p < p1; p++) {
        size_t nb = (size_t)nbr[p] * 128 + j;
        a0 += m0[nb]; a1 += m1[nb];
    }
    float sc = rsqrtf((float)deg[node] + 1.f);
    h0[idx] = sc * a0 + b0[j];
    h1[idx] = sc * a1 + b1[j];
}

__global__ void k_agg_hat(const int* __restrict__ ptr, const int* __restrict__ nbr,
                          const float* __restrict__ m_meta, const float* __restrict__ m_org,
                          const float* __restrict__ b_meta, const float* __restrict__ b_org,
                          const int* __restrict__ deg, const float* __restrict__ c_pr,
                          float* __restrict__ out_meta, float* __restrict__ out_org, int n) {
    int j = threadIdx.x & 127, li = threadIdx.x >> 7;
    int node = blockIdx.x * 2 + li;
    if (node >= n) return;
    int p0 = ptr[node], p1 = ptr[node + 1];
    size_t idx = (size_t)node * 128 + j;
    float a0 = m_meta[idx], a1 = m_org[idx];
    for (int p = p0; p < p1; p++) {
        size_t nb = (size_t)nbr[p] * 128 + j;
        a0 += m_meta[nb]; a1 += m_org[nb];
    }
    int dg = deg[node];
    float sc = rsqrtf((float)dg + 1.f);
    float pr = c_pr[node] * fmaxf((float)dg, 1.f);
    out_meta[idx] = (sc * a0 + b_meta[j]) * pr;
    out_org[idx]  = (sc * a1 + b_org[j]) * pr;
}

// ---------------- line-graph path ----------------
__global__ void k_ef(const int* __restrict__ src, const int* __restrict__ dst,
                     const int* __restrict__ eattr, const int* __restrict__ x,
                     const float* __restrict__ metafeat, const float* __restrict__ atom_emb,
                     const float* __restrict__ bond_emb, const float* __restrict__ meta_W,
                     const float* __restrict__ meta_b, const int* __restrict__ deg_lg,
                     ushort_t* __restrict__ u, int E) {
    __shared__ float W[16 * 128];
    __shared__ float bond[8 * 128];
    __shared__ float mb[128];
    for (int i = threadIdx.x; i < 16 * 128; i += blockDim.x) W[i] = meta_W[i];
    for (int i = threadIdx.x; i < 8 * 128; i += blockDim.x) bond[i] = bond_emb[i];
    if (threadIdx.x < 128) mb[threadIdx.x] = meta_b[threadIdx.x];
    __syncthreads();
    int j = threadIdx.x & 127, li = threadIdx.x >> 7;
    int e = blockIdx.x * 2 + li;
    if (e >= E) return;
    int s = src[e], d = dst[e], at = eattr[e];
    float nsum = atom_emb[(size_t)x[s] * 128 + j] + atom_emb[(size_t)x[d] * 128 + j];
    float msum = 2.f * mb[j];
    const float* ms = metafeat + (size_t)s * 16;
    const float* md = metafeat + (size_t)d * 16;
#pragma unroll
    for (int k = 0; k < 16; k++) msum = fmaf(ms[k] + md[k], W[k * 128 + j], msum);
    float val = bond[at * 128 + j] * nsum * msum;
    float sc = rsqrtf((float)deg_lg[e] + 1.f);
    u[(size_t)e * 128 + j] = f2bf(sc * eluf(val));
}

// fallback (R2): per-edge gather + fp32 atomic scatter into g0
__global__ void k_lg_scatter(const int* __restrict__ ptr_lg, const int* __restrict__ adj_lg,
                             const int* __restrict__ deg_lg, const ushort_t* __restrict__ u,
                             const int* __restrict__ src, const int* __restrict__ dst,
                             float* __restrict__ g0, int E) {
    int j = threadIdx.x & 127, li = threadIdx.x >> 7;
    int e = blockIdx.x * 2 + li;
    if (e >= E) return;
    int p0 = ptr_lg[e], p1 = ptr_lg[e + 1];
    float acc = bf2f(u[(size_t)e * 128 + j]);
    for (int p = p0; p < p1; p++) acc += bf2f(u[(size_t)adj_lg[p] * 128 + j]);
    float v = rsqrtf((float)deg_lg[e] + 1.f) * acc;
    atomicAdd(&g0[(size_t)src[e] * 128 + j], v);
    atomicAdd(&g0[(size_t)dst[e] * 128 + j], v);
}

// atomic-free: v[e] = sc_e*(u[e] + sum_{e' ~ e} u[e'])  (64 lanes/edge, uint = 2 bf16)
__global__ void k_lg_v(const int* __restrict__ ptr_lg, const int* __restrict__ adj_lg,
                       const int* __restrict__ deg_lg, const uint_t* __restrict__ u32,
                       uint_t* __restrict__ v32, int E) {
    int l = threadIdx.x & 63, li = threadIdx.x >> 6;
    int e = blockIdx.x * 4 + li;
    if (e >= E) return;
    int p0 = ptr_lg[e], p1 = ptr_lg[e + 1];
    uint_t self = u32[(size_t)e * 64 + l];
    float s0 = bflo(self), s1 = bfhi(self);
    for (int p = p0; p < p1; p++) {
        uint_t w = u32[(size_t)adj_lg[p] * 64 + l];
        s0 += bflo(w); s1 += bfhi(w);
    }
    float sc = rsqrtf((float)deg_lg[e] + 1.f);
    v32[(size_t)e * 64 + l] = packbf(sc * s0, sc * s1);
}

// g0[n] = sum over incident edges of v[eid]   (deterministic node-CSR gather)
__global__ void k_gate_edges_v(const int* __restrict__ ptr, const int* __restrict__ eid,
                               const uint_t* __restrict__ v32, float* __restrict__ g0, int n) {
    int l = threadIdx.x & 63, li = threadIdx.x >> 6;
    int node = blockIdx.x * 4 + li;
    if (node >= n) return;
    int p0 = ptr[node], p1 = ptr[node + 1];
    float s0 = 0.f, s1 = 0.f;
    for (int p = p0; p < p1; p++) {
        uint_t w = v32[(size_t)eid[p] * 64 + l];
        s0 += bflo(w); s1 += bfhi(w);
    }
    *reinterpret_cast<float2*>(g0 + (size_t)node * 128 + l * 2) = make_float2(s0, s1);
}

// ---------------- persistent pagerank (manual grid barrier) ----------------
// c = pr/deg formulation; NB blocks x PR_THREADS, co-resident by construction.
__global__ __launch_bounds__(PR_THREADS, 1) void k_pagerank(
    const int* __restrict__ ptr, const int* __restrict__ nbr,
    const int* __restrict__ deg, float* __restrict__ c_a, float* __restrict__ c_b,
    float* __restrict__ invdeg, int* __restrict__ cnt,
    int n, float base, float damp, float invN, int iters, int nb) {
    int gid = blockIdx.x * PR_THREADS + threadIdx.x;
    int stride = nb * PR_THREADS;
    for (int i = gid; i < n; i += stride) {
        float iv = 1.f / fmaxf((float)deg[i], 1.f);
        invdeg[i] = iv;
        c_a[i] = invN * iv;
    }
    float* cin = c_a;
    float* cout = c_b;
    for (int it = 1; it <= iters; ++it) {
        // grid barrier: release -> arrive -> spin -> acquire
        __syncthreads();
        if (threadIdx.x == 0) {
            __threadfence();
            atomicAdd(cnt, 1);
            int target = nb * it;
            while (atomicAdd(cnt, 0) < target) __builtin_amdgcn_s_sleep(2);
            __threadfence();
        }
        __syncthreads();
        for (int i = gid; i < n; i += stride) {
            float s = 0.f;
            int p0 = ptr[i], p1 = ptr[i + 1];
            for (int p = p0; p < p1; p++) s += cin[nbr[p]];
            cout[i] = (base + damp * s) * invdeg[i];
        }
        float* t = cin; cin = cout; cout = t;
    }
    // final result lives in c_a for even iters (kernel-end flush publishes it)
}

// ---------------- pooling + heads ----------------
__global__ void k_pool(const float* __restrict__ out_meta, const float* __restrict__ out_org,
                       float* __restrict__ partial, int n) {
    int tid = threadIdx.x;
    const float* basep = (tid < 128) ? out_meta : out_org;
    int dim = tid & 127;
    float acc = 0.f;
    for (int i = blockIdx.x; i < n; i += gridDim.x) acc += basep[(size_t)i * 128 + dim];
    partial[blockIdx.x * 256 + tid] = acc;
}

__global__ void k_final(const float* __restrict__ partial, int nblocks,
                        const float* __restrict__ cat2_W, const float* __restrict__ cat2_b,
                        const float* __restrict__ pred_W, const float* __restrict__ pred_b,
                        float* __restrict__ out) {
    __shared__ float z[256];
    __shared__ float Z[128];
    int tid = threadIdx.x;
    float acc = 0.f;
    for (int p = 0; p < nblocks; p++) acc += partial[p * 256 + tid];
    z[tid] = acc;
    __syncthreads();
    if (tid < 128) {
        float s = cat2_b[tid];
        for (int k = 0; k < 256; k++) s = fmaf(z[k], cat2_W[k * 128 + tid], s);
        Z[tid] = s;
    }
    __syncthreads();
    if (tid < 12) {
        float s = pred_b[tid];
        for (int k = 0; k < 128; k++) s = fmaf(Z[k], pred_W[k * 12 + tid], s);
        out[tid] = s;
    }
}

// ---------------------------------------------------------------------------
extern "C" void kernel_launch(void* const* d_in, const int* in_sizes, int n_in,
                              void* d_out, int out_size, void* d_ws, size_t ws_size,
                              hipStream_t stream) {
    const int* x            = (const int*)d_in[0];
    const float* metafeat   = (const float*)d_in[1];
    const int* edge_attr    = (const int*)d_in[2];
    const int* edge_index   = (const int*)d_in[3];
    const int* lg_edge_index= (const int*)d_in[4];
    const float* atom_emb   = (const float*)d_in[5];
    const float* bond_emb   = (const float*)d_in[6];
    const float* meta_W     = (const float*)d_in[7];
    const float* meta_b     = (const float*)d_in[8];
    const float* org_W      = (const float*)d_in[9];
    const float* org_b      = (const float*)d_in[10];
    const float* org1_W     = (const float*)d_in[11];
    const float* org1_b     = (const float*)d_in[12];
    const float* mconv_W    = (const float*)d_in[13];
    const float* mconv_b    = (const float*)d_in[14];
    const float* mconv1_W   = (const float*)d_in[15];
    const float* mconv1_b   = (const float*)d_in[16];
    const float* lg_W       = (const float*)d_in[17];
    const float* lg_b       = (const float*)d_in[18];
    const float* cat2_W     = (const float*)d_in[21];
    const float* cat2_b     = (const float*)d_in[22];
    const float* pred_W     = (const float*)d_in[23];
    const float* pred_b     = (const float*)d_in[24];

    const int N = in_sizes[0];
    const int E = in_sizes[2];
    const int ELG = in_sizes[4] / 2;
    const int* src = edge_index;
    const int* dst = edge_index + E;
    const int* ls = lg_edge_index;
    const int* ld = lg_edge_index + ELG;

    // ---- workspace carve ----
    char* w = (char*)d_ws;
    auto alloc = [&](size_t bytes) -> void* {
        void* p = (void*)w;
        w += (bytes + 255) & ~(size_t)255;
        return p;
    };
    int* deg_n   = (int*)alloc((size_t)N * 4);
    int* ptr_n   = (int*)alloc((size_t)(N + 1) * 4);
    int* cur_n   = (int*)alloc((size_t)N * 4);
    int* adj_nbr = (int*)alloc((size_t)2 * E * 4);
    int* adj_eid = (int*)alloc((size_t)2 * E * 4);
    int* deg_lg  = (int*)alloc((size_t)E * 4);
    int* ptr_lg  = (int*)alloc((size_t)(E + 1) * 4);
    int* cur_lg  = (int*)alloc((size_t)E * 4);
    int* adj_lg  = (int*)alloc((size_t)2 * ELG * 4);
    int* bsum    = (int*)alloc((size_t)SCAN_NB * 4);
    int* prcnt   = (int*)alloc(256);
    float* c_a   = (float*)alloc((size_t)N * 4);
    float* c_b   = (float*)alloc((size_t)N * 4);
    float* invdg = (float*)alloc((size_t)N * 4);
    float* partial = (float*)alloc((size_t)POOL_BLOCKS * 256 * 4);
    float* gate  = (float*)alloc((size_t)N * 128 * 4);
    float* h_org  = (float*)alloc((size_t)N * 128 * 4);
    float* h_meta = (float*)alloc((size_t)N * 128 * 4);
    size_t nodeF = (size_t)N * 128;
    size_t reg_bytes = 4 * nodeF * 4;
    size_t u_bytes = (size_t)E * 128 * 2;
    float* reg = (float*)alloc(reg_bytes > u_bytes ? reg_bytes : u_bytes);
    float* nf0 = reg;
    float* mf0 = reg + nodeF;
    float* m0  = reg + 2 * nodeF;
    float* m1  = reg + 3 * nodeF;
    ushort_t* u = (ushort_t*)reg;
    // optional v buffer (atomic-free lg path) — only if workspace permits
    size_t used = (size_t)(w - (char*)d_ws);
    uint_t* vbuf = nullptr;
    if (ws_size >= used + u_bytes + 1024) vbuf = (uint_t*)alloc(u_bytes);
    (void)n_in; (void)out_size;

    float* out_pred = (float*)d_out;
    float* out_meta = out_pred + 12;
    float* out_org  = out_pred + 12 + nodeF;

    // ---- CSR build ----
    hipMemsetAsync(deg_n, 0, (size_t)N * 4, stream);
    hipMemsetAsync(deg_lg, 0, (size_t)E * 4, stream);
    hipMemsetAsync(prcnt, 0, 256, stream);
    k_count<<<(E + 255) / 256, 256, 0, stream>>>(src, dst, E, deg_n);
    {
        int C = (N + SCAN_NB - 1) / SCAN_NB;
        k_scan1<<<SCAN_NB, 256, 0, stream>>>(deg_n, N, C, bsum);
        k_scan2<<<1, 256, 0, stream>>>(bsum, SCAN_NB, ptr_n + N);
        k_scan3<<<SCAN_NB, 256, 0, stream>>>(deg_n, bsum, N, C, ptr_n, cur_n);
    }
    k_fill<<<(E + 255) / 256, 256, 0, stream>>>(src, dst, E, cur_n, adj_nbr, adj_eid, 2 * E);
    k_count<<<(ELG + 255) / 256, 256, 0, stream>>>(ls, ld, ELG, deg_lg);
    {
        int C = (E + SCAN_NB - 1) / SCAN_NB;
        k_scan1<<<SCAN_NB, 256, 0, stream>>>(deg_lg, E, C, bsum);
        k_scan2<<<1, 256, 0, stream>>>(bsum, SCAN_NB, ptr_lg + E);
        k_scan3<<<SCAN_NB, 256, 0, stream>>>(deg_lg, bsum, E, C, ptr_lg, cur_lg);
    }
    k_fill<<<(ELG + 255) / 256, 256, 0, stream>>>(ls, ld, ELG, cur_lg, adj_lg, nullptr, 2 * ELG);

    // ---- encoders + gate_n ----
    k_encoder<<<(N * 128 + 255) / 256, 256, 0, stream>>>(x, metafeat, atom_emb, meta_W, meta_b,
                                                         nf0, mf0, N);
    k_gate_node<<<(N + 1) / 2, 256, 0, stream>>>(ptr_n, adj_eid, edge_attr, bond_emb, gate, N);

    const int gb_n = (N + 127) / 128;

    // ---- GCN layer 1 ----
    k_gemm<1, 0><<<gb_n, 256, 0, stream>>>(nf0, gate, org_W, nullptr, deg_n, m0, N);
    k_gemm<1, 0><<<gb_n, 256, 0, stream>>>(mf0, gate, mconv_W, nullptr, deg_n, m1, N);
    k_agg_dual<<<(N + 1) / 2, 256, 0, stream>>>(ptr_n, adj_nbr, m0, m1, org_b, mconv_b,
                                                deg_n, h_org, h_meta, N);
    // region becomes u (bf16)

    // ---- line-graph path ----
    k_ef<<<(E + 1) / 2, 256, 0, stream>>>(src, dst, edge_attr, x, metafeat, atom_emb,
                                          bond_emb, meta_W, meta_b, deg_lg, u, E);
    if (vbuf) {
        k_lg_v<<<(E + 3) / 4, 256, 0, stream>>>(ptr_lg, adj_lg, deg_lg, (const uint_t*)u,
                                                vbuf, E);
        k_gate_edges_v<<<(N + 3) / 4, 256, 0, stream>>>(ptr_n, adj_eid, vbuf, gate, N);
    } else {
        hipMemsetAsync(gate, 0, nodeF * 4, stream);
        k_lg_scatter<<<(E + 1) / 2, 256, 0, stream>>>(ptr_lg, adj_lg, deg_lg, u, src, dst,
                                                      gate, E);
    }
    k_gemm<0, 1><<<gb_n, 256, 0, stream>>>(gate, nullptr, lg_W, lg_b, deg_n, gate, N);

    // ---- GCN layer 2 (gated) ----
    k_gemm<1, 0><<<gb_n, 256, 0, stream>>>(h_org, gate, org1_W, nullptr, deg_n, m0, N);
    k_gemm<1, 0><<<gb_n, 256, 0, stream>>>(h_meta, gate, mconv1_W, nullptr, deg_n, m1, N);

    // ---- pagerank: one persistent kernel, 100 iterations ----
    float invN = (float)(1.0 / (double)N);
    float base = (float)((1.0 - 0.85) / (double)N);
    int prNB = (N + PR_THREADS - 1) / PR_THREADS;   // 98 for N=50000; co-resident
    if (prNB > 256) prNB = 256;
    k_pagerank<<<prNB, PR_THREADS, 0, stream>>>(ptr_n, adj_nbr, deg_n, c_a, c_b, invdg,
                                                prcnt, N, base, 0.85f, invN, 100, prNB);
    float* pr_final = c_a;   // 100 (even) iterations end in c_a

    // ---- final agg + pagerank scale -> d_out, pooling, heads ----
    k_agg_hat<<<(N + 1) / 2, 256, 0, stream>>>(ptr_n, adj_nbr, m1, m0, mconv1_b, org1_b,
                                               deg_n, pr_final, out_meta, out_org, N);
    k_pool<<<POOL_BLOCKS, 256, 0, stream>>>(out_meta, out_org, partial, N);
    k_final<<<1, 256, 0, stream>>>(partial, POOL_BLOCKS, cat2_W, cat2_b, pred_W, pred_b, out_pred);
}

// Round 4
// 3235.642 us; speedup vs baseline: 1.4395x; 1.4395x over previous
//
#include <hip/hip_runtime.h>
#include <hip/hip_bf16.h>
#include <math.h>

// ---------------------------------------------------------------------------
// IMPGNN on MI355X. fp32 compute, bf16 edge intermediate u (2%-of-absmax tol).
// R4 vs R3:
//   - pagerank: persistent kernel (98 blocks, 9.5% occ, 1910 us) REVERTED to
//     100 graph-captured launches, but per-iter kernel rebuilt: ELL adjacency
//     (lane-major, coalesced), 4 lanes/node + shfl quad-reduce, 782 blocks.
//     ELL lives in the dead nf0 region (u is dead after scatter) - no new mem.
//   - agg_dual / agg_hat: float4 per lane (32 lanes/row, 8 nodes/block).
//   - line-graph path: known-quantity atomic scatter (R2, 712 us); v-path dropped.
// ---------------------------------------------------------------------------

#define POOL_BLOCKS 400
#define SCAN_NB 256
#define ELL_CAP 64   // per-node neighbor capacity in ELL; CSR fallback beyond

typedef unsigned short ushort_t;

__device__ __forceinline__ float eluf(float x) { return x > 0.f ? x : expm1f(x); }
__device__ __forceinline__ float bf2f(ushort_t v) {
    return __uint_as_float(((unsigned int)v) << 16);
}
__device__ __forceinline__ ushort_t f2bf(float f) {
    unsigned int u = __float_as_uint(f);
    unsigned int lsb = (u >> 16) & 1u;
    u += 0x7fffu + lsb;           // round-to-nearest-even
    return (ushort_t)(u >> 16);
}

// ---------------- CSR build ----------------
__global__ void k_count(const int* __restrict__ a, const int* __restrict__ b,
                        int E, int* __restrict__ deg) {
    int e = blockIdx.x * blockDim.x + threadIdx.x;
    if (e < E) { atomicAdd(&deg[a[e]], 1); atomicAdd(&deg[b[e]], 1); }
}

__global__ void k_scan1(const int* __restrict__ deg, int n, int C, int* __restrict__ bsum) {
    __shared__ int red[256];
    int b = blockIdx.x, tid = threadIdx.x;
    int base = b * C, end = min(base + C, n);
    int s = 0;
    for (int i = base + tid; i < end; i += 256) s += deg[i];
    red[tid] = s;
    __syncthreads();
    for (int off = 128; off > 0; off >>= 1) {
        if (tid < off) red[tid] += red[tid + off];
        __syncthreads();
    }
    if (tid == 0) bsum[b] = red[0];
}

__global__ void k_scan2(int* __restrict__ bsum, int NB, int* __restrict__ total_out) {
    __shared__ int s[256];
    int tid = threadIdx.x;
    int v = (tid < NB) ? bsum[tid] : 0;
    s[tid] = v;
    __syncthreads();
    for (int off = 1; off < 256; off <<= 1) {
        int w = (tid >= off) ? s[tid - off] : 0;
        __syncthreads();
        s[tid] += w;
        __syncthreads();
    }
    if (tid < NB) bsum[tid] = s[tid] - v;
    if (tid == 255) *total_out = s[255];
}

__global__ void k_scan3(const int* __restrict__ deg, const int* __restrict__ boff,
                        int n, int C, int* __restrict__ ptr, int* __restrict__ cur) {
    __shared__ int s[256];
    __shared__ int carry;
    int b = blockIdx.x, tid = threadIdx.x;
    int base = b * C, end = min(base + C, n);
    if (tid == 0) carry = boff[b];
    __syncthreads();
    for (int t = base; t < end; t += 256) {
        int i = t + tid;
        int v = (i < end) ? deg[i] : 0;
        s[tid] = v;
        __syncthreads();
        for (int off = 1; off < 256; off <<= 1) {
            int w = (tid >= off) ? s[tid - off] : 0;
            __syncthreads();
            s[tid] += w;
            __syncthreads();
        }
        int p = carry + s[tid] - v;
        if (i < end) { ptr[i] = p; cur[i] = p; }
        __syncthreads();
        if (tid == 0) carry += s[255];
        __syncthreads();
    }
}

__global__ void k_fill(const int* __restrict__ a, const int* __restrict__ b, int E,
                       int* __restrict__ cur, int* __restrict__ nbr,
                       int* __restrict__ eid, int cap) {
    int e = blockIdx.x * blockDim.x + threadIdx.x;
    if (e < E) {
        int s = a[e], d = b[e];
        int p = atomicAdd(&cur[s], 1);
        if (p < cap) { nbr[p] = d; if (eid) eid[p] = e; }
        int q = atomicAdd(&cur[d], 1);
        if (q < cap) { nbr[q] = s; if (eid) eid[q] = e; }
    }
}

// ---------------- encoders ----------------
__global__ void k_encoder(const int* __restrict__ x, const float* __restrict__ metafeat,
                          const float* __restrict__ atom_emb, const float* __restrict__ meta_W,
                          const float* __restrict__ meta_b, float* __restrict__ nf0,
                          float* __restrict__ mf0, int N) {
    __shared__ float W[16 * 128];
    __shared__ float bsh[128];
    for (int i = threadIdx.x; i < 16 * 128; i += blockDim.x) W[i] = meta_W[i];
    if (threadIdx.x < 128) bsh[threadIdx.x] = meta_b[threadIdx.x];
    __syncthreads();
    int idx = blockIdx.x * blockDim.x + threadIdx.x;
    if (idx < N * 128) {
        int i = idx >> 7, j = idx & 127;
        nf0[idx] = atom_emb[x[i] * 128 + j];
        const float* mrow = metafeat + i * 16;
        float acc = bsh[j];
#pragma unroll
        for (int k = 0; k < 16; k++) acc = fmaf(mrow[k], W[k * 128 + j], acc);
        mf0[idx] = acc;
    }
}

__global__ void k_gate_node(const int* __restrict__ ptr, const int* __restrict__ eid_arr,
                            const int* __restrict__ edge_attr, const float* __restrict__ bond_emb,
                            float* __restrict__ gate, int N) {
    __shared__ float bond[8 * 128];
    for (int i = threadIdx.x; i < 8 * 128; i += blockDim.x) bond[i] = bond_emb[i];
    __syncthreads();
    int j = threadIdx.x & 127, li = threadIdx.x >> 7;
    int node = blockIdx.x * 2 + li;
    if (node >= N) return;
    int p0 = ptr[node], p1 = ptr[node + 1];
    float g = 0.f;
    for (int p = p0; p < p1; p++) g += bond[edge_attr[eid_arr[p]] * 128 + j];
    gate[(size_t)node * 128 + j] = g;
}

// ---------------- GEMM ----------------
template <int GATED, int EPI>
__global__ __launch_bounds__(256, 4) void k_gemm(
    const float* __restrict__ X, const float* __restrict__ G,
    const float* __restrict__ W, const float* __restrict__ bias,
    const int* __restrict__ deg, float* __restrict__ out, int M) {
    __shared__ float As[128][33];
    __shared__ float Bs[32][128];
    int tid = threadIdx.x;
    int tx = tid & 15, ty = tid >> 4;
    int row0 = blockIdx.x * 128;

    float acc[8][8];
#pragma unroll
    for (int i = 0; i < 8; i++)
#pragma unroll
        for (int j = 0; j < 8; j++) acc[i][j] = 0.f;

    for (int h = 0; h < 4; h++) {
#pragma unroll
        for (int p = 0; p < 4; p++) {
            int idx = p * 256 + tid;
            int kk = idx >> 5, cg = idx & 31;
            float4 w = *reinterpret_cast<const float4*>(W + (h * 32 + kk) * 128 + cg * 4);
            *reinterpret_cast<float4*>(&Bs[kk][cg * 4]) = w;
        }
        int kg = tid & 7, rr = tid >> 3;
#pragma unroll
        for (int p = 0; p < 4; p++) {
            int r = p * 32 + rr;
            int grow = row0 + r;
            int k = h * 32 + kg * 4;
            float4 av;
            if (grow < M) {
                float4 xv = *reinterpret_cast<const float4*>(X + (size_t)grow * 128 + k);
                if (GATED) {
                    float4 gv = *reinterpret_cast<const float4*>(G + (size_t)grow * 128 + k);
                    av.x = eluf(xv.x * gv.x); av.y = eluf(xv.y * gv.y);
                    av.z = eluf(xv.z * gv.z); av.w = eluf(xv.w * gv.w);
                } else av = xv;
            } else av = make_float4(0.f, 0.f, 0.f, 0.f);
            As[r][kg * 4 + 0] = av.x; As[r][kg * 4 + 1] = av.y;
            As[r][kg * 4 + 2] = av.z; As[r][kg * 4 + 3] = av.w;
        }
        __syncthreads();
#pragma unroll 8
        for (int k = 0; k < 32; k++) {
            float a[8], b[8];
#pragma unroll
            for (int i = 0; i < 8; i++) a[i] = As[ty * 8 + i][k];
            float4 b0 = *reinterpret_cast<const float4*>(&Bs[k][tx * 4]);
            float4 b1 = *reinterpret_cast<const float4*>(&Bs[k][64 + tx * 4]);
            b[0] = b0.x; b[1] = b0.y; b[2] = b0.z; b[3] = b0.w;
            b[4] = b1.x; b[5] = b1.y; b[6] = b1.z; b[7] = b1.w;
#pragma unroll
            for (int i = 0; i < 8; i++)
#pragma unroll
                for (int j = 0; j < 8; j++) acc[i][j] = fmaf(a[i], b[j], acc[i][j]);
        }
        __syncthreads();
    }
#pragma unroll
    for (int i = 0; i < 8; i++) {
        int r = row0 + ty * 8 + i;
        if (r < M) {
            float4 o0, o1;
            if (EPI == 0) {
                float sc = rsqrtf((float)deg[r] + 1.0f);
                o0 = make_float4(acc[i][0] * sc, acc[i][1] * sc, acc[i][2] * sc, acc[i][3] * sc);
                o1 = make_float4(acc[i][4] * sc, acc[i][5] * sc, acc[i][6] * sc, acc[i][7] * sc);
            } else {
                float dg = (float)deg[r];
                float4 ba = *reinterpret_cast<const float4*>(bias + tx * 4);
                float4 bb = *reinterpret_cast<const float4*>(bias + 64 + tx * 4);
                o0 = make_float4(acc[i][0] + dg * ba.x, acc[i][1] + dg * ba.y,
                                 acc[i][2] + dg * ba.z, acc[i][3] + dg * ba.w);
                o1 = make_float4(acc[i][4] + dg * bb.x, acc[i][5] + dg * bb.y,
                                 acc[i][6] + dg * bb.z, acc[i][7] + dg * bb.w);
            }
            *reinterpret_cast<float4*>(out + (size_t)r * 128 + tx * 4) = o0;
            *reinterpret_cast<float4*>(out + (size_t)r * 128 + 64 + tx * 4) = o1;
        }
    }
}

// ---------------- node aggregations: float4, 32 lanes/row, 8 nodes/block ----
__global__ void k_agg_dual(const int* __restrict__ ptr, const int* __restrict__ nbr,
                           const float* __restrict__ m0, const float* __restrict__ m1,
                           const float* __restrict__ b0, const float* __restrict__ b1,
                           const int* __restrict__ deg, float* __restrict__ h0,
                           float* __restrict__ h1, int n) {
    int c = threadIdx.x & 31, li = threadIdx.x >> 5;
    int node = blockIdx.x * 8 + li;
    if (node >= n) return;
    int p0 = ptr[node], p1 = ptr[node + 1];
    size_t idx = (size_t)node * 128 + c * 4;
    float4 a0 = *reinterpret_cast<const float4*>(m0 + idx);
    float4 a1 = *reinterpret_cast<const float4*>(m1 + idx);
    for (int p = p0; p < p1; p++) {
        size_t nb = (size_t)nbr[p] * 128 + c * 4;
        float4 v0 = *reinterpret_cast<const float4*>(m0 + nb);
        float4 v1 = *reinterpret_cast<const float4*>(m1 + nb);
        a0.x += v0.x; a0.y += v0.y; a0.z += v0.z; a0.w += v0.w;
        a1.x += v1.x; a1.y += v1.y; a1.z += v1.z; a1.w += v1.w;
    }
    float sc = rsqrtf((float)deg[node] + 1.f);
    float4 bb0 = *reinterpret_cast<const float4*>(b0 + c * 4);
    float4 bb1 = *reinterpret_cast<const float4*>(b1 + c * 4);
    float4 o0 = make_float4(sc * a0.x + bb0.x, sc * a0.y + bb0.y,
                            sc * a0.z + bb0.z, sc * a0.w + bb0.w);
    float4 o1 = make_float4(sc * a1.x + bb1.x, sc * a1.y + bb1.y,
                            sc * a1.z + bb1.z, sc * a1.w + bb1.w);
    *reinterpret_cast<float4*>(h0 + idx) = o0;
    *reinterpret_cast<float4*>(h1 + idx) = o1;
}

__global__ void k_agg_hat(const int* __restrict__ ptr, const int* __restrict__ nbr,
                          const float* __restrict__ m_meta, const float* __restrict__ m_org,
                          const float* __restrict__ b_meta, const float* __restrict__ b_org,
                          const int* __restrict__ deg, const float* __restrict__ c_pr,
                          float* __restrict__ out_meta, float* __restrict__ out_org, int n) {
    int c = threadIdx.x & 31, li = threadIdx.x >> 5;
    int node = blockIdx.x * 8 + li;
    if (node >= n) return;
    int p0 = ptr[node], p1 = ptr[node + 1];
    size_t idx = (size_t)node * 128 + c * 4;
    float4 a0 = *reinterpret_cast<const float4*>(m_meta + idx);
    float4 a1 = *reinterpret_cast<const float4*>(m_org + idx);
    for (int p = p0; p < p1; p++) {
        size_t nb = (size_t)nbr[p] * 128 + c * 4;
        float4 v0 = *reinterpret_cast<const float4*>(m_meta + nb);
        float4 v1 = *reinterpret_cast<const float4*>(m_org + nb);
        a0.x += v0.x; a0.y += v0.y; a0.z += v0.z; a0.w += v0.w;
        a1.x += v1.x; a1.y += v1.y; a1.z += v1.z; a1.w += v1.w;
    }
    int dg = deg[node];
    float sc = rsqrtf((float)dg + 1.f);
    float pr = c_pr[node] * fmaxf((float)dg, 1.f);
    float4 bb0 = *reinterpret_cast<const float4*>(b_meta + c * 4);
    float4 bb1 = *reinterpret_cast<const float4*>(b_org + c * 4);
    float4 o0 = make_float4((sc * a0.x + bb0.x) * pr, (sc * a0.y + bb0.y) * pr,
                            (sc * a0.z + bb0.z) * pr, (sc * a0.w + bb0.w) * pr);
    float4 o1 = make_float4((sc * a1.x + bb1.x) * pr, (sc * a1.y + bb1.y) * pr,
                            (sc * a1.z + bb1.z) * pr, (sc * a1.w + bb1.w) * pr);
    *reinterpret_cast<float4*>(out_meta + idx) = o0;
    *reinterpret_cast<float4*>(out_org + idx) = o1;
}

// ---------------- line-graph path ----------------
__global__ void k_ef(const int* __restrict__ src, const int* __restrict__ dst,
                     const int* __restrict__ eattr, const int* __restrict__ x,
                     const float* __restrict__ metafeat, const float* __restrict__ atom_emb,
                     const float* __restrict__ bond_emb, const float* __restrict__ meta_W,
                     const float* __restrict__ meta_b, const int* __restrict__ deg_lg,
                     ushort_t* __restrict__ u, int E) {
    __shared__ float W[16 * 128];
    __shared__ float bond[8 * 128];
    __shared__ float mb[128];
    for (int i = threadIdx.x; i < 16 * 128; i += blockDim.x) W[i] = meta_W[i];
    for (int i = threadIdx.x; i < 8 * 128; i += blockDim.x) bond[i] = bond_emb[i];
    if (threadIdx.x < 128) mb[threadIdx.x] = meta_b[threadIdx.x];
    __syncthreads();
    int j = threadIdx.x & 127, li = threadIdx.x >> 7;
    int e = blockIdx.x * 2 + li;
    if (e >= E) return;
    int s = src[e], d = dst[e], at = eattr[e];
    float nsum = atom_emb[(size_t)x[s] * 128 + j] + atom_emb[(size_t)x[d] * 128 + j];
    float msum = 2.f * mb[j];
    const float* ms = metafeat + (size_t)s * 16;
    const float* md = metafeat + (size_t)d * 16;
#pragma unroll
    for (int k = 0; k < 16; k++) msum = fmaf(ms[k] + md[k], W[k * 128 + j], msum);
    float val = bond[at * 128 + j] * nsum * msum;
    float sc = rsqrtf((float)deg_lg[e] + 1.f);
    u[(size_t)e * 128 + j] = f2bf(sc * eluf(val));
}

// per edge: v = sc*(u[e] + sum_{e'~e} u[e']); atomic scatter into g0[src],g0[dst]
__global__ void k_lg_scatter(const int* __restrict__ ptr_lg, const int* __restrict__ adj_lg,
                             const int* __restrict__ deg_lg, const ushort_t* __restrict__ u,
                             const int* __restrict__ src, const int* __restrict__ dst,
                             float* __restrict__ g0, int E) {
    int j = threadIdx.x & 127, li = threadIdx.x >> 7;
    int e = blockIdx.x * 2 + li;
    if (e >= E) return;
    int p0 = ptr_lg[e], p1 = ptr_lg[e + 1];
    float acc = bf2f(u[(size_t)e * 128 + j]);
    for (int p = p0; p < p1; p++) acc += bf2f(u[(size_t)adj_lg[p] * 128 + j]);
    float v = rsqrtf((float)deg_lg[e] + 1.f) * acc;
    atomicAdd(&g0[(size_t)src[e] * 128 + j], v);
    atomicAdd(&g0[(size_t)dst[e] * 128 + j], v);
}

// ---------------- pagerank: ELL, 4 lanes/node, 100 launches ----------------
__global__ void k_pr_init(const int* __restrict__ deg, float* __restrict__ c,
                          float* __restrict__ invdeg, int n, float invN) {
    int i = blockIdx.x * blockDim.x + threadIdx.x;
    if (i < n) {
        float iv = 1.f / fmaxf((float)deg[i], 1.f);
        invdeg[i] = iv;
        c[i] = invN * iv;
    }
}

// lane-major ELL: ell[k*4N + 4*node + t] = k-th group neighbor (slot 4k+t)
__global__ void k_ell_build(const int* __restrict__ ptr, const int* __restrict__ nbr,
                            int* __restrict__ ell, int N) {
    int tid = blockIdx.x * blockDim.x + threadIdx.x;
    int node = tid >> 2, t = tid & 3;
    if (node >= N) return;
    int p0 = ptr[node];
    int dg = ptr[node + 1] - p0;
    if (dg > ELL_CAP) dg = ELL_CAP;
    int stride = N * 4;
    for (int k = 0; 4 * k + t < dg; k++)
        ell[k * stride + tid] = nbr[p0 + 4 * k + t];
}

__global__ void k_pr_ell(const int* __restrict__ ell, const int* __restrict__ ptr,
                         const int* __restrict__ nbr, const float* __restrict__ invdeg,
                         const float* __restrict__ cin, float* __restrict__ cout,
                         int N, float base, float damp) {
    int tid = blockIdx.x * blockDim.x + threadIdx.x;
    int node = tid >> 2, t = tid & 3;
    if (node >= N) return;
    int p0 = ptr[node], p1 = ptr[node + 1];
    int dg = p1 - p0;
    int dgc = dg > ELL_CAP ? ELL_CAP : dg;
    int stride = N * 4;
    float s = 0.f;
    for (int k = 0; 4 * k + t < dgc; k++) s += cin[ell[k * stride + tid]];
    for (int p = p0 + ELL_CAP + t; p < p1; p += 4) s += cin[nbr[p]];  // rare overflow
    s += __shfl_xor(s, 1);
    s += __shfl_xor(s, 2);
    if (t == 0) cout[node] = (base + damp * s) * invdeg[node];
}

// ---------------- pooling + heads ----------------
__global__ void k_pool(const float* __restrict__ out_meta, const float* __restrict__ out_org,
                       float* __restrict__ partial, int n) {
    int tid = threadIdx.x;
    const float* basep = (tid < 128) ? out_meta : out_org;
    int dim = tid & 127;
    float acc = 0.f;
    for (int i = blockIdx.x; i < n; i += gridDim.x) acc += basep[(size_t)i * 128 + dim];
    partial[blockIdx.x * 256 + tid] = acc;
}

__global__ void k_final(const float* __restrict__ partial, int nblocks,
                        const float* __restrict__ cat2_W, const float* __restrict__ cat2_b,
                        const float* __restrict__ pred_W, const float* __restrict__ pred_b,
                        float* __restrict__ out) {
    __shared__ float z[256];
    __shared__ float Z[128];
    int tid = threadIdx.x;
    float acc = 0.f;
    for (int p = 0; p < nblocks; p++) acc += partial[p * 256 + tid];
    z[tid] = acc;
    __syncthreads();
    if (tid < 128) {
        float s = cat2_b[tid];
        for (int k = 0; k < 256; k++) s = fmaf(z[k], cat2_W[k * 128 + tid], s);
        Z[tid] = s;
    }
    __syncthreads();
    if (tid < 12) {
        float s = pred_b[tid];
        for (int k = 0; k < 128; k++) s = fmaf(Z[k], pred_W[k * 12 + tid], s);
        out[tid] = s;
    }
}

// ---------------------------------------------------------------------------
extern "C" void kernel_launch(void* const* d_in, const int* in_sizes, int n_in,
                              void* d_out, int out_size, void* d_ws, size_t ws_size,
                              hipStream_t stream) {
    const int* x            = (const int*)d_in[0];
    const float* metafeat   = (const float*)d_in[1];
    const int* edge_attr    = (const int*)d_in[2];
    const int* edge_index   = (const int*)d_in[3];
    const int* lg_edge_index= (const int*)d_in[4];
    const float* atom_emb   = (const float*)d_in[5];
    const float* bond_emb   = (const float*)d_in[6];
    const float* meta_W     = (const float*)d_in[7];
    const float* meta_b     = (const float*)d_in[8];
    const float* org_W      = (const float*)d_in[9];
    const float* org_b      = (const float*)d_in[10];
    const float* org1_W     = (const float*)d_in[11];
    const float* org1_b     = (const float*)d_in[12];
    const float* mconv_W    = (const float*)d_in[13];
    const float* mconv_b    = (const float*)d_in[14];
    const float* mconv1_W   = (const float*)d_in[15];
    const float* mconv1_b   = (const float*)d_in[16];
    const float* lg_W       = (const float*)d_in[17];
    const float* lg_b       = (const float*)d_in[18];
    const float* cat2_W     = (const float*)d_in[21];
    const float* cat2_b     = (const float*)d_in[22];
    const float* pred_W     = (const float*)d_in[23];
    const float* pred_b     = (const float*)d_in[24];

    const int N = in_sizes[0];
    const int E = in_sizes[2];
    const int ELG = in_sizes[4] / 2;
    const int* src = edge_index;
    const int* dst = edge_index + E;
    const int* ls = lg_edge_index;
    const int* ld = lg_edge_index + ELG;

    // ---- workspace carve (~205 MB, same footprint as R2) ----
    char* w = (char*)d_ws;
    auto alloc = [&](size_t bytes) -> void* {
        void* p = (void*)w;
        w += (bytes + 255) & ~(size_t)255;
        return p;
    };
    int* deg_n   = (int*)alloc((size_t)N * 4);
    int* ptr_n   = (int*)alloc((size_t)(N + 1) * 4);
    int* cur_n   = (int*)alloc((size_t)N * 4);
    int* adj_nbr = (int*)alloc((size_t)2 * E * 4);
    int* adj_eid = (int*)alloc((size_t)2 * E * 4);
    int* deg_lg  = (int*)alloc((size_t)E * 4);
    int* ptr_lg  = (int*)alloc((size_t)(E + 1) * 4);
    int* cur_lg  = (int*)alloc((size_t)E * 4);
    int* adj_lg  = (int*)alloc((size_t)2 * ELG * 4);
    int* bsum    = (int*)alloc((size_t)SCAN_NB * 4);
    float* c_a   = (float*)alloc((size_t)N * 4);
    float* c_b   = (float*)alloc((size_t)N * 4);
    float* invdg = (float*)alloc((size_t)N * 4);
    float* partial = (float*)alloc((size_t)POOL_BLOCKS * 256 * 4);
    float* gate  = (float*)alloc((size_t)N * 128 * 4);
    float* h_org  = (float*)alloc((size_t)N * 128 * 4);
    float* h_meta = (float*)alloc((size_t)N * 128 * 4);
    size_t nodeF = (size_t)N * 128;
    size_t reg_bytes = 4 * nodeF * 4;
    size_t u_bytes = (size_t)E * 128 * 2;
    float* reg = (float*)alloc(reg_bytes > u_bytes ? reg_bytes : u_bytes);
    float* nf0 = reg;
    float* mf0 = reg + nodeF;
    float* m0  = reg + 2 * nodeF;
    float* m1  = reg + 3 * nodeF;
    ushort_t* u = (ushort_t*)reg;
    // ELL aliases the nf0/mf0 quarters (51.2 MB, dead after layer-1 GEMMs and
    // after u dies post-scatter; layer-2 GEMMs only overwrite the m0/m1 half).
    int* ell = (int*)reg;   // needs ELL_CAP/4 * 4N ints = 12.8 MB << 51.2 MB
    (void)n_in; (void)out_size; (void)ws_size;

    float* out_pred = (float*)d_out;
    float* out_meta = out_pred + 12;
    float* out_org  = out_pred + 12 + nodeF;

    // ---- CSR build ----
    hipMemsetAsync(deg_n, 0, (size_t)N * 4, stream);
    hipMemsetAsync(deg_lg, 0, (size_t)E * 4, stream);
    k_count<<<(E + 255) / 256, 256, 0, stream>>>(src, dst, E, deg_n);
    {
        int C = (N + SCAN_NB - 1) / SCAN_NB;
        k_scan1<<<SCAN_NB, 256, 0, stream>>>(deg_n, N, C, bsum);
        k_scan2<<<1, 256, 0, stream>>>(bsum, SCAN_NB, ptr_n + N);
        k_scan3<<<SCAN_NB, 256, 0, stream>>>(deg_n, bsum, N, C, ptr_n, cur_n);
    }
    k_fill<<<(E + 255) / 256, 256, 0, stream>>>(src, dst, E, cur_n, adj_nbr, adj_eid, 2 * E);
    k_count<<<(ELG + 255) / 256, 256, 0, stream>>>(ls, ld, ELG, deg_lg);
    {
        int C = (E + SCAN_NB - 1) / SCAN_NB;
        k_scan1<<<SCAN_NB, 256, 0, stream>>>(deg_lg, E, C, bsum);
        k_scan2<<<1, 256, 0, stream>>>(bsum, SCAN_NB, ptr_lg + E);
        k_scan3<<<SCAN_NB, 256, 0, stream>>>(deg_lg, bsum, E, C, ptr_lg, cur_lg);
    }
    k_fill<<<(ELG + 255) / 256, 256, 0, stream>>>(ls, ld, ELG, cur_lg, adj_lg, nullptr, 2 * ELG);

    // ---- encoders + gate_n ----
    k_encoder<<<(N * 128 + 255) / 256, 256, 0, stream>>>(x, metafeat, atom_emb, meta_W, meta_b,
                                                         nf0, mf0, N);
    k_gate_node<<<(N + 1) / 2, 256, 0, stream>>>(ptr_n, adj_eid, edge_attr, bond_emb, gate, N);

    const int gb_n = (N + 127) / 128;

    // ---- GCN layer 1 ----
    k_gemm<1, 0><<<gb_n, 256, 0, stream>>>(nf0, gate, org_W, nullptr, deg_n, m0, N);
    k_gemm<1, 0><<<gb_n, 256, 0, stream>>>(mf0, gate, mconv_W, nullptr, deg_n, m1, N);
    k_agg_dual<<<(N + 7) / 8, 256, 0, stream>>>(ptr_n, adj_nbr, m0, m1, org_b, mconv_b,
                                                deg_n, h_org, h_meta, N);
    // reg region becomes u (bf16)

    // ---- line-graph path: u -> atomic scatter g0 -> gate_l GEMM (in place) ----
    k_ef<<<(E + 1) / 2, 256, 0, stream>>>(src, dst, edge_attr, x, metafeat, atom_emb,
                                          bond_emb, meta_W, meta_b, deg_lg, u, E);
    hipMemsetAsync(gate, 0, nodeF * 4, stream);
    k_lg_scatter<<<(E + 1) / 2, 256, 0, stream>>>(ptr_lg, adj_lg, deg_lg, u, src, dst, gate, E);
    k_gemm<0, 1><<<gb_n, 256, 0, stream>>>(gate, nullptr, lg_W, lg_b, deg_n, gate, N);

    // ---- GCN layer 2 (gated) ----
    k_gemm<1, 0><<<gb_n, 256, 0, stream>>>(h_org, gate, org1_W, nullptr, deg_n, m0, N);
    k_gemm<1, 0><<<gb_n, 256, 0, stream>>>(h_meta, gate, mconv1_W, nullptr, deg_n, m1, N);
    // u dead; nf0/mf0 quarters free -> ELL

    // ---- pagerank: ELL build + 100 graph-captured launches ----
    float invN = (float)(1.0 / (double)N);
    float base = (float)((1.0 - 0.85) / (double)N);
    k_pr_init<<<(N + 255) / 256, 256, 0, stream>>>(deg_n, c_a, invdg, N, invN);
    int prb = (4 * N + 255) / 256;   // 782 blocks: 4 lanes per node
    k_ell_build<<<prb, 256, 0, stream>>>(ptr_n, adj_nbr, ell, N);
    float* pin = c_a;
    float* pout = c_b;
    for (int it = 0; it < 100; ++it) {
        k_pr_ell<<<prb, 256, 0, stream>>>(ell, ptr_n, adj_nbr, invdg, pin, pout, N,
                                          base, 0.85f);
        float* t = pin; pin = pout; pout = t;
    }

    // ---- final agg + pagerank scale -> d_out, pooling, heads ----
    k_agg_hat<<<(N + 7) / 8, 256, 0, stream>>>(ptr_n, adj_nbr, m1, m0, mconv1_b, org1_b,
                                               deg_n, pin, out_meta, out_org, N);
    k_pool<<<POOL_BLOCKS, 256, 0, stream>>>(out_meta, out_org, partial, N);
    k_final<<<1, 256, 0, stream>>>(partial, POOL_BLOCKS, cat2_W, cat2_b, pred_W, pred_b, out_pred);
}

// Round 5
// 2821.811 us; speedup vs baseline: 1.6506x; 1.1467x over previous
//
#include <hip/hip_runtime.h>
#include <hip/hip_bf16.h>
#include <math.h>

// ---------------------------------------------------------------------------
// IMPGNN on MI355X. fp32 compute; bf16 for gathered intermediates (u, m0, m1).
// R5 vs R4:
//   - m0/m1 (GEMM outputs feeding aggregations) stored bf16: agg gather
//     traffic halves (819 -> 410 MB per agg kernel). fp32 accumulate.
//   - pagerank truncated to 48 iters (error <= 0.85^48 ~ 1.6e-4 relative on
//     pr -> ~6e-9 absolute on outputs; threshold is 2% of output absmax).
//   - line-graph scatter unchanged (R6 target).
// ---------------------------------------------------------------------------

#define POOL_BLOCKS 400
#define SCAN_NB 256
#define ELL_CAP 64
#define PR_ITERS 48   // even: result ends in c_a

typedef unsigned short ushort_t;
typedef unsigned int uint_t;

__device__ __forceinline__ float eluf(float x) { return x > 0.f ? x : expm1f(x); }
__device__ __forceinline__ float bf2f(ushort_t v) {
    return __uint_as_float(((unsigned int)v) << 16);
}
__device__ __forceinline__ ushort_t f2bf(float f) {
    unsigned int u = __float_as_uint(f);
    unsigned int lsb = (u >> 16) & 1u;
    u += 0x7fffu + lsb;           // round-to-nearest-even
    return (ushort_t)(u >> 16);
}
__device__ __forceinline__ float bflo(uint_t v) { return __uint_as_float(v << 16); }
__device__ __forceinline__ float bfhi(uint_t v) { return __uint_as_float(v & 0xffff0000u); }
__device__ __forceinline__ uint_t packbf(float a, float b) {
    return (uint_t)f2bf(a) | ((uint_t)f2bf(b) << 16);
}

// ---------------- CSR build ----------------
__global__ void k_count(const int* __restrict__ a, const int* __restrict__ b,
                        int E, int* __restrict__ deg) {
    int e = blockIdx.x * blockDim.x + threadIdx.x;
    if (e < E) { atomicAdd(&deg[a[e]], 1); atomicAdd(&deg[b[e]], 1); }
}

__global__ void k_scan1(const int* __restrict__ deg, int n, int C, int* __restrict__ bsum) {
    __shared__ int red[256];
    int b = blockIdx.x, tid = threadIdx.x;
    int base = b * C, end = min(base + C, n);
    int s = 0;
    for (int i = base + tid; i < end; i += 256) s += deg[i];
    red[tid] = s;
    __syncthreads();
    for (int off = 128; off > 0; off >>= 1) {
        if (tid < off) red[tid] += red[tid + off];
        __syncthreads();
    }
    if (tid == 0) bsum[b] = red[0];
}

__global__ void k_scan2(int* __restrict__ bsum, int NB, int* __restrict__ total_out) {
    __shared__ int s[256];
    int tid = threadIdx.x;
    int v = (tid < NB) ? bsum[tid] : 0;
    s[tid] = v;
    __syncthreads();
    for (int off = 1; off < 256; off <<= 1) {
        int w = (tid >= off) ? s[tid - off] : 0;
        __syncthreads();
        s[tid] += w;
        __syncthreads();
    }
    if (tid < NB) bsum[tid] = s[tid] - v;
    if (tid == 255) *total_out = s[255];
}

__global__ void k_scan3(const int* __restrict__ deg, const int* __restrict__ boff,
                        int n, int C, int* __restrict__ ptr, int* __restrict__ cur) {
    __shared__ int s[256];
    __shared__ int carry;
    int b = blockIdx.x, tid = threadIdx.x;
    int base = b * C, end = min(base + C, n);
    if (tid == 0) carry = boff[b];
    __syncthreads();
    for (int t = base; t < end; t += 256) {
        int i = t + tid;
        int v = (i < end) ? deg[i] : 0;
        s[tid] = v;
        __syncthreads();
        for (int off = 1; off < 256; off <<= 1) {
            int w = (tid >= off) ? s[tid - off] : 0;
            __syncthreads();
            s[tid] += w;
            __syncthreads();
        }
        int p = carry + s[tid] - v;
        if (i < end) { ptr[i] = p; cur[i] = p; }
        __syncthreads();
        if (tid == 0) carry += s[255];
        __syncthreads();
    }
}

__global__ void k_fill(const int* __restrict__ a, const int* __restrict__ b, int E,
                       int* __restrict__ cur, int* __restrict__ nbr,
                       int* __restrict__ eid, int cap) {
    int e = blockIdx.x * blockDim.x + threadIdx.x;
    if (e < E) {
        int s = a[e], d = b[e];
        int p = atomicAdd(&cur[s], 1);
        if (p < cap) { nbr[p] = d; if (eid) eid[p] = e; }
        int q = atomicAdd(&cur[d], 1);
        if (q < cap) { nbr[q] = s; if (eid) eid[q] = e; }
    }
}

// ---------------- encoders ----------------
__global__ void k_encoder(const int* __restrict__ x, const float* __restrict__ metafeat,
                          const float* __restrict__ atom_emb, const float* __restrict__ meta_W,
                          const float* __restrict__ meta_b, float* __restrict__ nf0,
                          float* __restrict__ mf0, int N) {
    __shared__ float W[16 * 128];
    __shared__ float bsh[128];
    for (int i = threadIdx.x; i < 16 * 128; i += blockDim.x) W[i] = meta_W[i];
    if (threadIdx.x < 128) bsh[threadIdx.x] = meta_b[threadIdx.x];
    __syncthreads();
    int idx = blockIdx.x * blockDim.x + threadIdx.x;
    if (idx < N * 128) {
        int i = idx >> 7, j = idx & 127;
        nf0[idx] = atom_emb[x[i] * 128 + j];
        const float* mrow = metafeat + i * 16;
        float acc = bsh[j];
#pragma unroll
        for (int k = 0; k < 16; k++) acc = fmaf(mrow[k], W[k * 128 + j], acc);
        mf0[idx] = acc;
    }
}

__global__ void k_gate_node(const int* __restrict__ ptr, const int* __restrict__ eid_arr,
                            const int* __restrict__ edge_attr, const float* __restrict__ bond_emb,
                            float* __restrict__ gate, int N) {
    __shared__ float bond[8 * 128];
    for (int i = threadIdx.x; i < 8 * 128; i += blockDim.x) bond[i] = bond_emb[i];
    __syncthreads();
    int j = threadIdx.x & 127, li = threadIdx.x >> 7;
    int node = blockIdx.x * 2 + li;
    if (node >= N) return;
    int p0 = ptr[node], p1 = ptr[node + 1];
    float g = 0.f;
    for (int p = p0; p < p1; p++) g += bond[edge_attr[eid_arr[p]] * 128 + j];
    gate[(size_t)node * 128 + j] = g;
}

// ---------------- GEMM ----------------
// GATED: A = elu(X*G) else A = X.
// EPI 0: out = rsqrt(deg+1)*acc   (OBF16: packed bf16 out, pitch 128 bf16)
// EPI 1: out = acc + deg*bias     (fp32 out)
template <int GATED, int EPI, int OBF16>
__global__ __launch_bounds__(256, 4) void k_gemm(
    const float* __restrict__ X, const float* __restrict__ G,
    const float* __restrict__ W, const float* __restrict__ bias,
    const int* __restrict__ deg, void* __restrict__ outv, int M) {
    __shared__ float As[128][33];
    __shared__ float Bs[32][128];
    int tid = threadIdx.x;
    int tx = tid & 15, ty = tid >> 4;
    int row0 = blockIdx.x * 128;

    float acc[8][8];
#pragma unroll
    for (int i = 0; i < 8; i++)
#pragma unroll
        for (int j = 0; j < 8; j++) acc[i][j] = 0.f;

    for (int h = 0; h < 4; h++) {
#pragma unroll
        for (int p = 0; p < 4; p++) {
            int idx = p * 256 + tid;
            int kk = idx >> 5, cg = idx & 31;
            float4 w = *reinterpret_cast<const float4*>(W + (h * 32 + kk) * 128 + cg * 4);
            *reinterpret_cast<float4*>(&Bs[kk][cg * 4]) = w;
        }
        int kg = tid & 7, rr = tid >> 3;
#pragma unroll
        for (int p = 0; p < 4; p++) {
            int r = p * 32 + rr;
            int grow = row0 + r;
            int k = h * 32 + kg * 4;
            float4 av;
            if (grow < M) {
                float4 xv = *reinterpret_cast<const float4*>(X + (size_t)grow * 128 + k);
                if (GATED) {
                    float4 gv = *reinterpret_cast<const float4*>(G + (size_t)grow * 128 + k);
                    av.x = eluf(xv.x * gv.x); av.y = eluf(xv.y * gv.y);
                    av.z = eluf(xv.z * gv.z); av.w = eluf(xv.w * gv.w);
                } else av = xv;
            } else av = make_float4(0.f, 0.f, 0.f, 0.f);
            As[r][kg * 4 + 0] = av.x; As[r][kg * 4 + 1] = av.y;
            As[r][kg * 4 + 2] = av.z; As[r][kg * 4 + 3] = av.w;
        }
        __syncthreads();
#pragma unroll 8
        for (int k = 0; k < 32; k++) {
            float a[8], b[8];
#pragma unroll
            for (int i = 0; i < 8; i++) a[i] = As[ty * 8 + i][k];
            float4 b0 = *reinterpret_cast<const float4*>(&Bs[k][tx * 4]);
            float4 b1 = *reinterpret_cast<const float4*>(&Bs[k][64 + tx * 4]);
            b[0] = b0.x; b[1] = b0.y; b[2] = b0.z; b[3] = b0.w;
            b[4] = b1.x; b[5] = b1.y; b[6] = b1.z; b[7] = b1.w;
#pragma unroll
            for (int i = 0; i < 8; i++)
#pragma unroll
                for (int j = 0; j < 8; j++) acc[i][j] = fmaf(a[i], b[j], acc[i][j]);
        }
        __syncthreads();
    }
#pragma unroll
    for (int i = 0; i < 8; i++) {
        int r = row0 + ty * 8 + i;
        if (r < M) {
            if (EPI == 0 && OBF16) {
                float sc = rsqrtf((float)deg[r] + 1.0f);
                uint_t* ob = (uint_t*)outv;   // pitch 64 uints (128 bf16)
                uint2 p0, p1;
                p0.x = packbf(acc[i][0] * sc, acc[i][1] * sc);
                p0.y = packbf(acc[i][2] * sc, acc[i][3] * sc);
                p1.x = packbf(acc[i][4] * sc, acc[i][5] * sc);
                p1.y = packbf(acc[i][6] * sc, acc[i][7] * sc);
                *reinterpret_cast<uint2*>(ob + (size_t)r * 64 + tx * 2) = p0;
                *reinterpret_cast<uint2*>(ob + (size_t)r * 64 + 32 + tx * 2) = p1;
            } else {
                float* out = (float*)outv;
                float4 o0, o1;
                if (EPI == 0) {
                    float sc = rsqrtf((float)deg[r] + 1.0f);
                    o0 = make_float4(acc[i][0] * sc, acc[i][1] * sc, acc[i][2] * sc, acc[i][3] * sc);
                    o1 = make_float4(acc[i][4] * sc, acc[i][5] * sc, acc[i][6] * sc, acc[i][7] * sc);
                } else {
                    float dg = (float)deg[r];
                    float4 ba = *reinterpret_cast<const float4*>(bias + tx * 4);
                    float4 bb = *reinterpret_cast<const float4*>(bias + 64 + tx * 4);
                    o0 = make_float4(acc[i][0] + dg * ba.x, acc[i][1] + dg * ba.y,
                                     acc[i][2] + dg * ba.z, acc[i][3] + dg * ba.w);
                    o1 = make_float4(acc[i][4] + dg * bb.x, acc[i][5] + dg * bb.y,
                                     acc[i][6] + dg * bb.z, acc[i][7] + dg * bb.w);
                }
                *reinterpret_cast<float4*>(out + (size_t)r * 128 + tx * 4) = o0;
                *reinterpret_cast<float4*>(out + (size_t)r * 128 + 64 + tx * 4) = o1;
            }
        }
    }
}

// ---------------- node aggregations: bf16 gathers, fp32 accumulate ----------
// 32 lanes/row (4 bf16 = one uint2 per lane), 8 nodes/block
__global__ void k_agg_dual(const int* __restrict__ ptr, const int* __restrict__ nbr,
                           const uint_t* __restrict__ m0, const uint_t* __restrict__ m1,
                           const float* __restrict__ b0, const float* __restrict__ b1,
                           const int* __restrict__ deg, float* __restrict__ h0,
                           float* __restrict__ h1, int n) {
    int c = threadIdx.x & 31, li = threadIdx.x >> 5;
    int node = blockIdx.x * 8 + li;
    if (node >= n) return;
    int p0 = ptr[node], p1 = ptr[node + 1];
    size_t idx = (size_t)node * 64 + c * 2;    // uint index, pitch 64
    uint2 s0 = *reinterpret_cast<const uint2*>(m0 + idx);
    uint2 s1 = *reinterpret_cast<const uint2*>(m1 + idx);
    float a00 = bflo(s0.x), a01 = bfhi(s0.x), a02 = bflo(s0.y), a03 = bfhi(s0.y);
    float a10 = bflo(s1.x), a11 = bfhi(s1.x), a12 = bflo(s1.y), a13 = bfhi(s1.y);
    for (int p = p0; p < p1; p++) {
        size_t nb = (size_t)nbr[p] * 64 + c * 2;
        uint2 v0 = *reinterpret_cast<const uint2*>(m0 + nb);
        uint2 v1 = *reinterpret_cast<const uint2*>(m1 + nb);
        a00 += bflo(v0.x); a01 += bfhi(v0.x); a02 += bflo(v0.y); a03 += bfhi(v0.y);
        a10 += bflo(v1.x); a11 += bfhi(v1.x); a12 += bflo(v1.y); a13 += bfhi(v1.y);
    }
    float sc = rsqrtf((float)deg[node] + 1.f);
    float4 bb0 = *reinterpret_cast<const float4*>(b0 + c * 4);
    float4 bb1 = *reinterpret_cast<const float4*>(b1 + c * 4);
    size_t o = (size_t)node * 128 + c * 4;
    *reinterpret_cast<float4*>(h0 + o) = make_float4(sc * a00 + bb0.x, sc * a01 + bb0.y,
                                                     sc * a02 + bb0.z, sc * a03 + bb0.w);
    *reinterpret_cast<float4*>(h1 + o) = make_float4(sc * a10 + bb1.x, sc * a11 + bb1.y,
                                                     sc * a12 + bb1.z, sc * a13 + bb1.w);
}

__global__ void k_agg_hat(const int* __restrict__ ptr, const int* __restrict__ nbr,
                          const uint_t* __restrict__ m_meta, const uint_t* __restrict__ m_org,
                          const float* __restrict__ b_meta, const float* __restrict__ b_org,
                          const int* __restrict__ deg, const float* __restrict__ c_pr,
                          float* __restrict__ out_meta, float* __restrict__ out_org, int n) {
    int c = threadIdx.x & 31, li = threadIdx.x >> 5;
    int node = blockIdx.x * 8 + li;
    if (node >= n) return;
    int p0 = ptr[node], p1 = ptr[node + 1];
    size_t idx = (size_t)node * 64 + c * 2;
    uint2 s0 = *reinterpret_cast<const uint2*>(m_meta + idx);
    uint2 s1 = *reinterpret_cast<const uint2*>(m_org + idx);
    float a00 = bflo(s0.x), a01 = bfhi(s0.x), a02 = bflo(s0.y), a03 = bfhi(s0.y);
    float a10 = bflo(s1.x), a11 = bfhi(s1.x), a12 = bflo(s1.y), a13 = bfhi(s1.y);
    for (int p = p0; p < p1; p++) {
        size_t nb = (size_t)nbr[p] * 64 + c * 2;
        uint2 v0 = *reinterpret_cast<const uint2*>(m_meta + nb);
        uint2 v1 = *reinterpret_cast<const uint2*>(m_org + nb);
        a00 += bflo(v0.x); a01 += bfhi(v0.x); a02 += bflo(v0.y); a03 += bfhi(v0.y);
        a10 += bflo(v1.x); a11 += bfhi(v1.x); a12 += bflo(v1.y); a13 += bfhi(v1.y);
    }
    int dg = deg[node];
    float sc = rsqrtf((float)dg + 1.f);
    float pr = c_pr[node] * fmaxf((float)dg, 1.f);
    float4 bb0 = *reinterpret_cast<const float4*>(b_meta + c * 4);
    float4 bb1 = *reinterpret_cast<const float4*>(b_org + c * 4);
    size_t o = (size_t)node * 128 + c * 4;
    *reinterpret_cast<float4*>(out_meta + o) =
        make_float4((sc * a00 + bb0.x) * pr, (sc * a01 + bb0.y) * pr,
                    (sc * a02 + bb0.z) * pr, (sc * a03 + bb0.w) * pr);
    *reinterpret_cast<float4*>(out_org + o) =
        make_float4((sc * a10 + bb1.x) * pr, (sc * a11 + bb1.y) * pr,
                    (sc * a12 + bb1.z) * pr, (sc * a13 + bb1.w) * pr);
}

// ---------------- line-graph path ----------------
__global__ void k_ef(const int* __restrict__ src, const int* __restrict__ dst,
                     const int* __restrict__ eattr, const int* __restrict__ x,
                     const float* __restrict__ metafeat, const float* __restrict__ atom_emb,
                     const float* __restrict__ bond_emb, const float* __restrict__ meta_W,
                     const float* __restrict__ meta_b, const int* __restrict__ deg_lg,
                     ushort_t* __restrict__ u, int E) {
    __shared__ float W[16 * 128];
    __shared__ float bond[8 * 128];
    __shared__ float mb[128];
    for (int i = threadIdx.x; i < 16 * 128; i += blockDim.x) W[i] = meta_W[i];
    for (int i = threadIdx.x; i < 8 * 128; i += blockDim.x) bond[i] = bond_emb[i];
    if (threadIdx.x < 128) mb[threadIdx.x] = meta_b[threadIdx.x];
    __syncthreads();
    int j = threadIdx.x & 127, li = threadIdx.x >> 7;
    int e = blockIdx.x * 2 + li;
    if (e >= E) return;
    int s = src[e], d = dst[e], at = eattr[e];
    float nsum = atom_emb[(size_t)x[s] * 128 + j] + atom_emb[(size_t)x[d] * 128 + j];
    float msum = 2.f * mb[j];
    const float* ms = metafeat + (size_t)s * 16;
    const float* md = metafeat + (size_t)d * 16;
#pragma unroll
    for (int k = 0; k < 16; k++) msum = fmaf(ms[k] + md[k], W[k * 128 + j], msum);
    float val = bond[at * 128 + j] * nsum * msum;
    float sc = rsqrtf((float)deg_lg[e] + 1.f);
    u[(size_t)e * 128 + j] = f2bf(sc * eluf(val));
}

__global__ void k_lg_scatter(const int* __restrict__ ptr_lg, const int* __restrict__ adj_lg,
                             const int* __restrict__ deg_lg, const ushort_t* __restrict__ u,
                             const int* __restrict__ src, const int* __restrict__ dst,
                             float* __restrict__ g0, int E) {
    int j = threadIdx.x & 127, li = threadIdx.x >> 7;
    int e = blockIdx.x * 2 + li;
    if (e >= E) return;
    int p0 = ptr_lg[e], p1 = ptr_lg[e + 1];
    float acc = bf2f(u[(size_t)e * 128 + j]);
    for (int p = p0; p < p1; p++) acc += bf2f(u[(size_t)adj_lg[p] * 128 + j]);
    float v = rsqrtf((float)deg_lg[e] + 1.f) * acc;
    atomicAdd(&g0[(size_t)src[e] * 128 + j], v);
    atomicAdd(&g0[(size_t)dst[e] * 128 + j], v);
}

// ---------------- pagerank: ELL, 4 lanes/node ----------------
__global__ void k_pr_init(const int* __restrict__ deg, float* __restrict__ c,
                          float* __restrict__ invdeg, int n, float invN) {
    int i = blockIdx.x * blockDim.x + threadIdx.x;
    if (i < n) {
        float iv = 1.f / fmaxf((float)deg[i], 1.f);
        invdeg[i] = iv;
        c[i] = invN * iv;
    }
}

__global__ void k_ell_build(const int* __restrict__ ptr, const int* __restrict__ nbr,
                            int* __restrict__ ell, int N) {
    int tid = blockIdx.x * blockDim.x + threadIdx.x;
    int node = tid >> 2, t = tid & 3;
    if (node >= N) return;
    int p0 = ptr[node];
    int dg = ptr[node + 1] - p0;
    if (dg > ELL_CAP) dg = ELL_CAP;
    int stride = N * 4;
    for (int k = 0; 4 * k + t < dg; k++)
        ell[k * stride + tid] = nbr[p0 + 4 * k + t];
}

__global__ void k_pr_ell(const int* __restrict__ ell, const int* __restrict__ ptr,
                         const int* __restrict__ nbr, const float* __restrict__ invdeg,
                         const float* __restrict__ cin, float* __restrict__ cout,
                         int N, float base, float damp) {
    int tid = blockIdx.x * blockDim.x + threadIdx.x;
    int node = tid >> 2, t = tid & 3;
    if (node >= N) return;
    int p0 = ptr[node], p1 = ptr[node + 1];
    int dg = p1 - p0;
    int dgc = dg > ELL_CAP ? ELL_CAP : dg;
    int stride = N * 4;
    float s = 0.f;
    for (int k = 0; 4 * k + t < dgc; k++) s += cin[ell[k * stride + tid]];
    for (int p = p0 + ELL_CAP + t; p < p1; p += 4) s += cin[nbr[p]];
    s += __shfl_xor(s, 1);
    s += __shfl_xor(s, 2);
    if (t == 0) cout[node] = (base + damp * s) * invdeg[node];
}

// ---------------- pooling + heads ----------------
__global__ void k_pool(const float* __restrict__ out_meta, const float* __restrict__ out_org,
                       float* __restrict__ partial, int n) {
    int tid = threadIdx.x;
    const float* basep = (tid < 128) ? out_meta : out_org;
    int dim = tid & 127;
    float acc = 0.f;
    for (int i = blockIdx.x; i < n; i += gridDim.x) acc += basep[(size_t)i * 128 + dim];
    partial[blockIdx.x * 256 + tid] = acc;
}

__global__ void k_final(const float* __restrict__ partial, int nblocks,
                        const float* __restrict__ cat2_W, const float* __restrict__ cat2_b,
                        const float* __restrict__ pred_W, const float* __restrict__ pred_b,
                        float* __restrict__ out) {
    __shared__ float z[256];
    __shared__ float Z[128];
    int tid = threadIdx.x;
    float acc = 0.f;
    for (int p = 0; p < nblocks; p++) acc += partial[p * 256 + tid];
    z[tid] = acc;
    __syncthreads();
    if (tid < 128) {
        float s = cat2_b[tid];
        for (int k = 0; k < 256; k++) s = fmaf(z[k], cat2_W[k * 128 + tid], s);
        Z[tid] = s;
    }
    __syncthreads();
    if (tid < 12) {
        float s = pred_b[tid];
        for (int k = 0; k < 128; k++) s = fmaf(Z[k], pred_W[k * 12 + tid], s);
        out[tid] = s;
    }
}

// ---------------------------------------------------------------------------
extern "C" void kernel_launch(void* const* d_in, const int* in_sizes, int n_in,
                              void* d_out, int out_size, void* d_ws, size_t ws_size,
                              hipStream_t stream) {
    const int* x            = (const int*)d_in[0];
    const float* metafeat   = (const float*)d_in[1];
    const int* edge_attr    = (const int*)d_in[2];
    const int* edge_index   = (const int*)d_in[3];
    const int* lg_edge_index= (const int*)d_in[4];
    const float* atom_emb   = (const float*)d_in[5];
    const float* bond_emb   = (const float*)d_in[6];
    const float* meta_W     = (const float*)d_in[7];
    const float* meta_b     = (const float*)d_in[8];
    const float* org_W      = (const float*)d_in[9];
    const float* org_b      = (const float*)d_in[10];
    const float* org1_W     = (const float*)d_in[11];
    const float* org1_b     = (const float*)d_in[12];
    const float* mconv_W    = (const float*)d_in[13];
    const float* mconv_b    = (const float*)d_in[14];
    const float* mconv1_W   = (const float*)d_in[15];
    const float* mconv1_b   = (const float*)d_in[16];
    const float* lg_W       = (const float*)d_in[17];
    const float* lg_b       = (const float*)d_in[18];
    const float* cat2_W     = (const float*)d_in[21];
    const float* cat2_b     = (const float*)d_in[22];
    const float* pred_W     = (const float*)d_in[23];
    const float* pred_b     = (const float*)d_in[24];

    const int N = in_sizes[0];
    const int E = in_sizes[2];
    const int ELG = in_sizes[4] / 2;
    const int* src = edge_index;
    const int* dst = edge_index + E;
    const int* ls = lg_edge_index;
    const int* ld = lg_edge_index + ELG;

    // ---- workspace carve ----
    char* w = (char*)d_ws;
    auto alloc = [&](size_t bytes) -> void* {
        void* p = (void*)w;
        w += (bytes + 255) & ~(size_t)255;
        return p;
    };
    int* deg_n   = (int*)alloc((size_t)N * 4);
    int* ptr_n   = (int*)alloc((size_t)(N + 1) * 4);
    int* cur_n   = (int*)alloc((size_t)N * 4);
    int* adj_nbr = (int*)alloc((size_t)2 * E * 4);
    int* adj_eid = (int*)alloc((size_t)2 * E * 4);
    int* deg_lg  = (int*)alloc((size_t)E * 4);
    int* ptr_lg  = (int*)alloc((size_t)(E + 1) * 4);
    int* cur_lg  = (int*)alloc((size_t)E * 4);
    int* adj_lg  = (int*)alloc((size_t)2 * ELG * 4);
    int* bsum    = (int*)alloc((size_t)SCAN_NB * 4);
    float* c_a   = (float*)alloc((size_t)N * 4);
    float* c_b   = (float*)alloc((size_t)N * 4);
    float* invdg = (float*)alloc((size_t)N * 4);
    float* partial = (float*)alloc((size_t)POOL_BLOCKS * 256 * 4);
    float* gate  = (float*)alloc((size_t)N * 128 * 4);
    float* h_org  = (float*)alloc((size_t)N * 128 * 4);
    float* h_meta = (float*)alloc((size_t)N * 128 * 4);
    size_t nodeF = (size_t)N * 128;
    size_t reg_bytes = 4 * nodeF * 4;
    size_t u_bytes = (size_t)E * 128 * 2;
    float* reg = (float*)alloc(reg_bytes > u_bytes ? reg_bytes : u_bytes);
    float* nf0 = reg;
    float* mf0 = reg + nodeF;
    uint_t* m0 = (uint_t*)(reg + 2 * nodeF);   // bf16-packed, pitch 64 uints/row
    uint_t* m1 = (uint_t*)(reg + 3 * nodeF);
    ushort_t* u = (ushort_t*)reg;              // overlays nf0..m1 (dead by then)
    int* ell = (int*)reg;                      // overlays nf0 quarter after u dies
    (void)n_in; (void)out_size; (void)ws_size;

    float* out_pred = (float*)d_out;
    float* out_meta = out_pred + 12;
    float* out_org  = out_pred + 12 + nodeF;

    // ---- CSR build ----
    hipMemsetAsync(deg_n, 0, (size_t)N * 4, stream);
    hipMemsetAsync(deg_lg, 0, (size_t)E * 4, stream);
    k_count<<<(E + 255) / 256, 256, 0, stream>>>(src, dst, E, deg_n);
    {
        int C = (N + SCAN_NB - 1) / SCAN_NB;
        k_scan1<<<SCAN_NB, 256, 0, stream>>>(deg_n, N, C, bsum);
        k_scan2<<<1, 256, 0, stream>>>(bsum, SCAN_NB, ptr_n + N);
        k_scan3<<<SCAN_NB, 256, 0, stream>>>(deg_n, bsum, N, C, ptr_n, cur_n);
    }
    k_fill<<<(E + 255) / 256, 256, 0, stream>>>(src, dst, E, cur_n, adj_nbr, adj_eid, 2 * E);
    k_count<<<(ELG + 255) / 256, 256, 0, stream>>>(ls, ld, ELG, deg_lg);
    {
        int C = (E + SCAN_NB - 1) / SCAN_NB;
        k_scan1<<<SCAN_NB, 256, 0, stream>>>(deg_lg, E, C, bsum);
        k_scan2<<<1, 256, 0, stream>>>(bsum, SCAN_NB, ptr_lg + E);
        k_scan3<<<SCAN_NB, 256, 0, stream>>>(deg_lg, bsum, E, C, ptr_lg, cur_lg);
    }
    k_fill<<<(ELG + 255) / 256, 256, 0, stream>>>(ls, ld, ELG, cur_lg, adj_lg, nullptr, 2 * ELG);

    // ---- encoders + gate_n ----
    k_encoder<<<(N * 128 + 255) / 256, 256, 0, stream>>>(x, metafeat, atom_emb, meta_W, meta_b,
                                                         nf0, mf0, N);
    k_gate_node<<<(N + 1) / 2, 256, 0, stream>>>(ptr_n, adj_eid, edge_attr, bond_emb, gate, N);

    const int gb_n = (N + 127) / 128;

    // ---- GCN layer 1 (bf16 m0/m1 out) ----
    k_gemm<1, 0, 1><<<gb_n, 256, 0, stream>>>(nf0, gate, org_W, nullptr, deg_n, m0, N);
    k_gemm<1, 0, 1><<<gb_n, 256, 0, stream>>>(mf0, gate, mconv_W, nullptr, deg_n, m1, N);
    k_agg_dual<<<(N + 7) / 8, 256, 0, stream>>>(ptr_n, adj_nbr, m0, m1, org_b, mconv_b,
                                                deg_n, h_org, h_meta, N);
    // reg region becomes u (bf16)

    // ---- line-graph path ----
    k_ef<<<(E + 1) / 2, 256, 0, stream>>>(src, dst, edge_attr, x, metafeat, atom_emb,
                                          bond_emb, meta_W, meta_b, deg_lg, u, E);
    hipMemsetAsync(gate, 0, nodeF * 4, stream);
    k_lg_scatter<<<(E + 1) / 2, 256, 0, stream>>>(ptr_lg, adj_lg, deg_lg, u, src, dst, gate, E);
    k_gemm<0, 1, 0><<<gb_n, 256, 0, stream>>>(gate, nullptr, lg_W, lg_b, deg_n, gate, N);

    // ---- GCN layer 2 (gated, bf16 m0/m1 out) ----
    k_gemm<1, 0, 1><<<gb_n, 256, 0, stream>>>(h_org, gate, org1_W, nullptr, deg_n, m0, N);
    k_gemm<1, 0, 1><<<gb_n, 256, 0, stream>>>(h_meta, gate, mconv1_W, nullptr, deg_n, m1, N);
    // u dead; nf0 quarter free -> ELL

    // ---- pagerank: ELL build + PR_ITERS graph-captured launches ----
    float invN = (float)(1.0 / (double)N);
    float base = (float)((1.0 - 0.85) / (double)N);
    k_pr_init<<<(N + 255) / 256, 256, 0, stream>>>(deg_n, c_a, invdg, N, invN);
    int prb = (4 * N + 255) / 256;
    k_ell_build<<<prb, 256, 0, stream>>>(ptr_n, adj_nbr, ell, N);
    float* pin = c_a;
    float* pout = c_b;
    for (int it = 0; it < PR_ITERS; ++it) {
        k_pr_ell<<<prb, 256, 0, stream>>>(ell, ptr_n, adj_nbr, invdg, pin, pout, N,
                                          base, 0.85f);
        float* t = pin; pin = pout; pout = t;
    }

    // ---- final agg + pagerank scale -> d_out, pooling, heads ----
    k_agg_hat<<<(N + 7) / 8, 256, 0, stream>>>(ptr_n, adj_nbr, m1, m0, mconv1_b, org1_b,
                                               deg_n, pin, out_meta, out_org, N);
    k_pool<<<POOL_BLOCKS, 256, 0, stream>>>(out_meta, out_org, partial, N);
    k_final<<<1, 256, 0, stream>>>(partial, POOL_BLOCKS, cat2_W, cat2_b, pred_W, pred_b, out_pred);
}

// Round 6
// 2735.726 us; speedup vs baseline: 1.7026x; 1.0315x over previous
//
#include <hip/hip_runtime.h>
#include <hip/hip_bf16.h>
#include <math.h>

// ---------------------------------------------------------------------------
// IMPGNN on MI355X. fp32 accumulate everywhere; bf16 storage for all gathered
// / streamed intermediates (u, v, m0/m1, nf0, mf0, gate, h). Tol = 2% of
// output absmax; measured bf16-layer error ~0.05%/layer (K=128 averaging).
// R6 vs R5:
//   - lg path: atomic scatter (400 MB write-through) -> split atomic-free:
//     k_lg_v (v bf16) + k_gate_edges_v (node-CSR gather), both with unroll-4
//     index prefetch to break the serial dependent-gather chain.
//   - all node features bf16 (GEMM reads/writes bf16, pitch 64 uints).
//   - agg_dual/agg_hat: unroll-4 prefetch.
// ---------------------------------------------------------------------------

#define POOL_BLOCKS 400
#define SCAN_NB 256
#define ELL_CAP 64
#define PR_ITERS 48   // even: result ends in c_a

typedef unsigned short ushort_t;
typedef unsigned int uint_t;

__device__ __forceinline__ float eluf(float x) { return x > 0.f ? x : expm1f(x); }
__device__ __forceinline__ float bf2f(ushort_t v) {
    return __uint_as_float(((unsigned int)v) << 16);
}
__device__ __forceinline__ ushort_t f2bf(float f) {
    unsigned int u = __float_as_uint(f);
    unsigned int lsb = (u >> 16) & 1u;
    u += 0x7fffu + lsb;           // round-to-nearest-even
    return (ushort_t)(u >> 16);
}
__device__ __forceinline__ float bflo(uint_t v) { return __uint_as_float(v << 16); }
__device__ __forceinline__ float bfhi(uint_t v) { return __uint_as_float(v & 0xffff0000u); }
__device__ __forceinline__ uint_t packbf(float a, float b) {
    return (uint_t)f2bf(a) | ((uint_t)f2bf(b) << 16);
}

// ---------------- CSR build ----------------
__global__ void k_count(const int* __restrict__ a, const int* __restrict__ b,
                        int E, int* __restrict__ deg) {
    int e = blockIdx.x * blockDim.x + threadIdx.x;
    if (e < E) { atomicAdd(&deg[a[e]], 1); atomicAdd(&deg[b[e]], 1); }
}

__global__ void k_scan1(const int* __restrict__ deg, int n, int C, int* __restrict__ bsum) {
    __shared__ int red[256];
    int b = blockIdx.x, tid = threadIdx.x;
    int base = b * C, end = min(base + C, n);
    int s = 0;
    for (int i = base + tid; i < end; i += 256) s += deg[i];
    red[tid] = s;
    __syncthreads();
    for (int off = 128; off > 0; off >>= 1) {
        if (tid < off) red[tid] += red[tid + off];
        __syncthreads();
    }
    if (tid == 0) bsum[b] = red[0];
}

__global__ void k_scan2(int* __restrict__ bsum, int NB, int* __restrict__ total_out) {
    __shared__ int s[256];
    int tid = threadIdx.x;
    int v = (tid < NB) ? bsum[tid] : 0;
    s[tid] = v;
    __syncthreads();
    for (int off = 1; off < 256; off <<= 1) {
        int w = (tid >= off) ? s[tid - off] : 0;
        __syncthreads();
        s[tid] += w;
        __syncthreads();
    }
    if (tid < NB) bsum[tid] = s[tid] - v;
    if (tid == 255) *total_out = s[255];
}

__global__ void k_scan3(const int* __restrict__ deg, const int* __restrict__ boff,
                        int n, int C, int* __restrict__ ptr, int* __restrict__ cur) {
    __shared__ int s[256];
    __shared__ int carry;
    int b = blockIdx.x, tid = threadIdx.x;
    int base = b * C, end = min(base + C, n);
    if (tid == 0) carry = boff[b];
    __syncthreads();
    for (int t = base; t < end; t += 256) {
        int i = t + tid;
        int v = (i < end) ? deg[i] : 0;
        s[tid] = v;
        __syncthreads();
        for (int off = 1; off < 256; off <<= 1) {
            int w = (tid >= off) ? s[tid - off] : 0;
            __syncthreads();
            s[tid] += w;
            __syncthreads();
        }
        int p = carry + s[tid] - v;
        if (i < end) { ptr[i] = p; cur[i] = p; }
        __syncthreads();
        if (tid == 0) carry += s[255];
        __syncthreads();
    }
}

__global__ void k_fill(const int* __restrict__ a, const int* __restrict__ b, int E,
                       int* __restrict__ cur, int* __restrict__ nbr,
                       int* __restrict__ eid, int cap) {
    int e = blockIdx.x * blockDim.x + threadIdx.x;
    if (e < E) {
        int s = a[e], d = b[e];
        int p = atomicAdd(&cur[s], 1);
        if (p < cap) { nbr[p] = d; if (eid) eid[p] = e; }
        int q = atomicAdd(&cur[d], 1);
        if (q < cap) { nbr[q] = s; if (eid) eid[q] = e; }
    }
}

// ---------------- encoders (bf16 out) ----------------
// one thread per 2 dims: idx -> node = idx>>6, pair j2 = idx&63 (dims 2j2,2j2+1)
__global__ void k_encoder(const int* __restrict__ x, const float* __restrict__ metafeat,
                          const float* __restrict__ atom_emb, const float* __restrict__ meta_W,
                          const float* __restrict__ meta_b, uint_t* __restrict__ nf0,
                          uint_t* __restrict__ mf0, int N) {
    __shared__ float W[16 * 128];
    __shared__ float bsh[128];
    for (int i = threadIdx.x; i < 16 * 128; i += blockDim.x) W[i] = meta_W[i];
    if (threadIdx.x < 128) bsh[threadIdx.x] = meta_b[threadIdx.x];
    __syncthreads();
    int idx = blockIdx.x * blockDim.x + threadIdx.x;
    if (idx < N * 64) {
        int i = idx >> 6, j2 = idx & 63;
        float2 av = *reinterpret_cast<const float2*>(atom_emb + (size_t)x[i] * 128 + j2 * 2);
        nf0[idx] = packbf(av.x, av.y);
        const float* mrow = metafeat + (size_t)i * 16;
        float a0 = bsh[j2 * 2], a1 = bsh[j2 * 2 + 1];
#pragma unroll
        for (int k = 0; k < 16; k++) {
            float m = mrow[k];
            a0 = fmaf(m, W[k * 128 + j2 * 2], a0);
            a1 = fmaf(m, W[k * 128 + j2 * 2 + 1], a1);
        }
        mf0[idx] = packbf(a0, a1);
    }
}

// gate_n bf16: 64 lanes/node (2 dims each), 4 nodes/block
__global__ void k_gate_node(const int* __restrict__ ptr, const int* __restrict__ eid_arr,
                            const int* __restrict__ edge_attr, const float* __restrict__ bond_emb,
                            uint_t* __restrict__ gate, int N) {
    __shared__ float bond[8 * 128];
    for (int i = threadIdx.x; i < 8 * 128; i += blockDim.x) bond[i] = bond_emb[i];
    __syncthreads();
    int l = threadIdx.x & 63, li = threadIdx.x >> 6;
    int node = blockIdx.x * 4 + li;
    if (node >= N) return;
    int p0 = ptr[node], p1 = ptr[node + 1];
    float g0 = 0.f, g1 = 0.f;
    for (int p = p0; p < p1; p++) {
        int a = edge_attr[eid_arr[p]];
        float2 bv = *reinterpret_cast<const float2*>(&bond[a * 128 + l * 2]);
        g0 += bv.x; g1 += bv.y;
    }
    gate[(size_t)node * 64 + l] = packbf(g0, g1);
}

// ---------------- GEMM ----------------
// GATED: A = elu(X*G) else A = X. IBF16: X (and G) packed bf16, pitch 64.
// EPI 0: out = rsqrt(deg+1)*acc   EPI 1: out = acc + deg*bias
// OBF16: packed bf16 out (pitch 64)  else fp32 (pitch 128)
template <int GATED, int EPI, int IBF16, int OBF16>
__global__ __launch_bounds__(256, 4) void k_gemm(
    const void* __restrict__ Xv, const void* __restrict__ Gv,
    const float* __restrict__ W, const float* __restrict__ bias,
    const int* __restrict__ deg, void* __restrict__ outv, int M) {
    __shared__ float As[128][33];
    __shared__ float Bs[32][128];
    int tid = threadIdx.x;
    int tx = tid & 15, ty = tid >> 4;
    int row0 = blockIdx.x * 128;

    float acc[8][8];
#pragma unroll
    for (int i = 0; i < 8; i++)
#pragma unroll
        for (int j = 0; j < 8; j++) acc[i][j] = 0.f;

    for (int h = 0; h < 4; h++) {
#pragma unroll
        for (int p = 0; p < 4; p++) {
            int idx = p * 256 + tid;
            int kk = idx >> 5, cg = idx & 31;
            float4 w = *reinterpret_cast<const float4*>(W + (h * 32 + kk) * 128 + cg * 4);
            *reinterpret_cast<float4*>(&Bs[kk][cg * 4]) = w;
        }
        int kg = tid & 7, rr = tid >> 3;
#pragma unroll
        for (int p = 0; p < 4; p++) {
            int r = p * 32 + rr;
            int grow = row0 + r;
            float4 av;
            if (grow < M) {
                float x0, x1, x2, x3;
                if (IBF16) {
                    const uint_t* Xb = (const uint_t*)Xv;
                    uint2 xu = *reinterpret_cast<const uint2*>(
                        Xb + (size_t)grow * 64 + h * 16 + kg * 2);
                    x0 = bflo(xu.x); x1 = bfhi(xu.x); x2 = bflo(xu.y); x3 = bfhi(xu.y);
                } else {
                    const float* Xf = (const float*)Xv;
                    float4 xv = *reinterpret_cast<const float4*>(
                        Xf + (size_t)grow * 128 + h * 32 + kg * 4);
                    x0 = xv.x; x1 = xv.y; x2 = xv.z; x3 = xv.w;
                }
                if (GATED) {
                    const uint_t* Gb = (const uint_t*)Gv;
                    uint2 gu = *reinterpret_cast<const uint2*>(
                        Gb + (size_t)grow * 64 + h * 16 + kg * 2);
                    av.x = eluf(x0 * bflo(gu.x)); av.y = eluf(x1 * bfhi(gu.x));
                    av.z = eluf(x2 * bflo(gu.y)); av.w = eluf(x3 * bfhi(gu.y));
                } else {
                    av = make_float4(x0, x1, x2, x3);
                }
            } else av = make_float4(0.f, 0.f, 0.f, 0.f);
            As[r][kg * 4 + 0] = av.x; As[r][kg * 4 + 1] = av.y;
            As[r][kg * 4 + 2] = av.z; As[r][kg * 4 + 3] = av.w;
        }
        __syncthreads();
#pragma unroll 8
        for (int k = 0; k < 32; k++) {
            float a[8], b[8];
#pragma unroll
            for (int i = 0; i < 8; i++) a[i] = As[ty * 8 + i][k];
            float4 b0 = *reinterpret_cast<const float4*>(&Bs[k][tx * 4]);
            float4 b1 = *reinterpret_cast<const float4*>(&Bs[k][64 + tx * 4]);
            b[0] = b0.x; b[1] = b0.y; b[2] = b0.z; b[3] = b0.w;
            b[4] = b1.x; b[5] = b1.y; b[6] = b1.z; b[7] = b1.w;
#pragma unroll
            for (int i = 0; i < 8; i++)
#pragma unroll
                for (int j = 0; j < 8; j++) acc[i][j] = fmaf(a[i], b[j], acc[i][j]);
        }
        __syncthreads();
    }
#pragma unroll
    for (int i = 0; i < 8; i++) {
        int r = row0 + ty * 8 + i;
        if (r < M) {
            float o[8];
            if (EPI == 0) {
                float sc = rsqrtf((float)deg[r] + 1.0f);
#pragma unroll
                for (int j = 0; j < 8; j++) o[j] = acc[i][j] * sc;
            } else {
                float dg = (float)deg[r];
                float4 ba = *reinterpret_cast<const float4*>(bias + tx * 4);
                float4 bb = *reinterpret_cast<const float4*>(bias + 64 + tx * 4);
                o[0] = acc[i][0] + dg * ba.x; o[1] = acc[i][1] + dg * ba.y;
                o[2] = acc[i][2] + dg * ba.z; o[3] = acc[i][3] + dg * ba.w;
                o[4] = acc[i][4] + dg * bb.x; o[5] = acc[i][5] + dg * bb.y;
                o[6] = acc[i][6] + dg * bb.z; o[7] = acc[i][7] + dg * bb.w;
            }
            if (OBF16) {
                uint_t* ob = (uint_t*)outv;
                uint2 q0, q1;
                q0.x = packbf(o[0], o[1]); q0.y = packbf(o[2], o[3]);
                q1.x = packbf(o[4], o[5]); q1.y = packbf(o[6], o[7]);
                *reinterpret_cast<uint2*>(ob + (size_t)r * 64 + tx * 2) = q0;
                *reinterpret_cast<uint2*>(ob + (size_t)r * 64 + 32 + tx * 2) = q1;
            } else {
                float* out = (float*)outv;
                *reinterpret_cast<float4*>(out + (size_t)r * 128 + tx * 4) =
                    make_float4(o[0], o[1], o[2], o[3]);
                *reinterpret_cast<float4*>(out + (size_t)r * 128 + 64 + tx * 4) =
                    make_float4(o[4], o[5], o[6], o[7]);
            }
        }
    }
}

// ---------------- node aggregations: bf16 gather, unroll-4 prefetch ---------
// 32 lanes/row (uint2 = 4 dims), 8 nodes/block. h out bf16.
__global__ void k_agg_dual(const int* __restrict__ ptr, const int* __restrict__ nbr,
                           const uint_t* __restrict__ m0, const uint_t* __restrict__ m1,
                           const float* __restrict__ b0, const float* __restrict__ b1,
                           const int* __restrict__ deg, uint_t* __restrict__ h0,
                           uint_t* __restrict__ h1, int n) {
    int c = threadIdx.x & 31, li = threadIdx.x >> 5;
    int node = blockIdx.x * 8 + li;
    if (node >= n) return;
    int p0 = ptr[node], p1 = ptr[node + 1];
    size_t idx = (size_t)node * 64 + c * 2;
    uint2 s0 = *reinterpret_cast<const uint2*>(m0 + idx);
    uint2 s1 = *reinterpret_cast<const uint2*>(m1 + idx);
    float a00 = bflo(s0.x), a01 = bfhi(s0.x), a02 = bflo(s0.y), a03 = bfhi(s0.y);
    float a10 = bflo(s1.x), a11 = bfhi(s1.x), a12 = bflo(s1.y), a13 = bfhi(s1.y);
    int p = p0;
    for (; p + 4 <= p1; p += 4) {
        int i0 = nbr[p], i1 = nbr[p + 1], i2 = nbr[p + 2], i3 = nbr[p + 3];
        uint2 v00 = *reinterpret_cast<const uint2*>(m0 + (size_t)i0 * 64 + c * 2);
        uint2 v01 = *reinterpret_cast<const uint2*>(m0 + (size_t)i1 * 64 + c * 2);
        uint2 v02 = *reinterpret_cast<const uint2*>(m0 + (size_t)i2 * 64 + c * 2);
        uint2 v03 = *reinterpret_cast<const uint2*>(m0 + (size_t)i3 * 64 + c * 2);
        uint2 v10 = *reinterpret_cast<const uint2*>(m1 + (size_t)i0 * 64 + c * 2);
        uint2 v11 = *reinterpret_cast<const uint2*>(m1 + (size_t)i1 * 64 + c * 2);
        uint2 v12 = *reinterpret_cast<const uint2*>(m1 + (size_t)i2 * 64 + c * 2);
        uint2 v13 = *reinterpret_cast<const uint2*>(m1 + (size_t)i3 * 64 + c * 2);
        a00 += bflo(v00.x) + bflo(v01.x) + bflo(v02.x) + bflo(v03.x);
        a01 += bfhi(v00.x) + bfhi(v01.x) + bfhi(v02.x) + bfhi(v03.x);
        a02 += bflo(v00.y) + bflo(v01.y) + bflo(v02.y) + bflo(v03.y);
        a03 += bfhi(v00.y) + bfhi(v01.y) + bfhi(v02.y) + bfhi(v03.y);
        a10 += bflo(v10.x) + bflo(v11.x) + bflo(v12.x) + bflo(v13.x);
        a11 += bfhi(v10.x) + bfhi(v11.x) + bfhi(v12.x) + bfhi(v13.x);
        a12 += bflo(v10.y) + bflo(v11.y) + bflo(v12.y) + bflo(v13.y);
        a13 += bfhi(v10.y) + bfhi(v11.y) + bfhi(v12.y) + bfhi(v13.y);
    }
    for (; p < p1; p++) {
        size_t nb = (size_t)nbr[p] * 64 + c * 2;
        uint2 v0 = *reinterpret_cast<const uint2*>(m0 + nb);
        uint2 v1 = *reinterpret_cast<const uint2*>(m1 + nb);
        a00 += bflo(v0.x); a01 += bfhi(v0.x); a02 += bflo(v0.y); a03 += bfhi(v0.y);
        a10 += bflo(v1.x); a11 += bfhi(v1.x); a12 += bflo(v1.y); a13 += bfhi(v1.y);
    }
    float sc = rsqrtf((float)deg[node] + 1.f);
    float4 bb0 = *reinterpret_cast<const float4*>(b0 + c * 4);
    float4 bb1 = *reinterpret_cast<const float4*>(b1 + c * 4);
    uint2 o0, o1;
    o0.x = packbf(sc * a00 + bb0.x, sc * a01 + bb0.y);
    o0.y = packbf(sc * a02 + bb0.z, sc * a03 + bb0.w);
    o1.x = packbf(sc * a10 + bb1.x, sc * a11 + bb1.y);
    o1.y = packbf(sc * a12 + bb1.z, sc * a13 + bb1.w);
    *reinterpret_cast<uint2*>(h0 + idx) = o0;
    *reinterpret_cast<uint2*>(h1 + idx) = o1;
}

__global__ void k_agg_hat(const int* __restrict__ ptr, const int* __restrict__ nbr,
                          const uint_t* __restrict__ m_meta, const uint_t* __restrict__ m_org,
                          const float* __restrict__ b_meta, const float* __restrict__ b_org,
                          const int* __restrict__ deg, const float* __restrict__ c_pr,
                          float* __restrict__ out_meta, float* __restrict__ out_org, int n) {
    int c = threadIdx.x & 31, li = threadIdx.x >> 5;
    int node = blockIdx.x * 8 + li;
    if (node >= n) return;
    int p0 = ptr[node], p1 = ptr[node + 1];
    size_t idx = (size_t)node * 64 + c * 2;
    uint2 s0 = *reinterpret_cast<const uint2*>(m_meta + idx);
    uint2 s1 = *reinterpret_cast<const uint2*>(m_org + idx);
    float a00 = bflo(s0.x), a01 = bfhi(s0.x), a02 = bflo(s0.y), a03 = bfhi(s0.y);
    float a10 = bflo(s1.x), a11 = bfhi(s1.x), a12 = bflo(s1.y), a13 = bfhi(s1.y);
    int p = p0;
    for (; p + 4 <= p1; p += 4) {
        int i0 = nbr[p], i1 = nbr[p + 1], i2 = nbr[p + 2], i3 = nbr[p + 3];
        uint2 v00 = *reinterpret_cast<const uint2*>(m_meta + (size_t)i0 * 64 + c * 2);
        uint2 v01 = *reinterpret_cast<const uint2*>(m_meta + (size_t)i1 * 64 + c * 2);
        uint2 v02 = *reinterpret_cast<const uint2*>(m_meta + (size_t)i2 * 64 + c * 2);
        uint2 v03 = *reinterpret_cast<const uint2*>(m_meta + (size_t)i3 * 64 + c * 2);
        uint2 v10 = *reinterpret_cast<const uint2*>(m_org + (size_t)i0 * 64 + c * 2);
        uint2 v11 = *reinterpret_cast<const uint2*>(m_org + (size_t)i1 * 64 + c * 2);
        uint2 v12 = *reinterpret_cast<const uint2*>(m_org + (size_t)i2 * 64 + c * 2);
        uint2 v13 = *reinterpret_cast<const uint2*>(m_org + (size_t)i3 * 64 + c * 2);
        a00 += bflo(v00.x) + bflo(v01.x) + bflo(v02.x) + bflo(v03.x);
        a01 += bfhi(v00.x) + bfhi(v01.x) + bfhi(v02.x) + bfhi(v03.x);
        a02 += bflo(v00.y) + bflo(v01.y) + bflo(v02.y) + bflo(v03.y);
        a03 += bfhi(v00.y) + bfhi(v01.y) + bfhi(v02.y) + bfhi(v03.y);
        a10 += bflo(v10.x) + bflo(v11.x) + bflo(v12.x) + bflo(v13.x);
        a11 += bfhi(v10.x) + bfhi(v11.x) + bfhi(v12.x) + bfhi(v13.x);
        a12 += bflo(v10.y) + bflo(v11.y) + bflo(v12.y) + bflo(v13.y);
        a13 += bfhi(v10.y) + bfhi(v11.y) + bfhi(v12.y) + bfhi(v13.y);
    }
    for (; p < p1; p++) {
        size_t nb = (size_t)nbr[p] * 64 + c * 2;
        uint2 v0 = *reinterpret_cast<const uint2*>(m_meta + nb);
        uint2 v1 = *reinterpret_cast<const uint2*>(m_org + nb);
        a00 += bflo(v0.x); a01 += bfhi(v0.x); a02 += bflo(v0.y); a03 += bfhi(v0.y);
        a10 += bflo(v1.x); a11 += bfhi(v1.x); a12 += bflo(v1.y); a13 += bfhi(v1.y);
    }
    int dg = deg[node];
    float sc = rsqrtf((float)dg + 1.f);
    float pr = c_pr[node] * fmaxf((float)dg, 1.f);
    float4 bb0 = *reinterpret_cast<const float4*>(b_meta + c * 4);
    float4 bb1 = *reinterpret_cast<const float4*>(b_org + c * 4);
    size_t o = (size_t)node * 128 + c * 4;
    *reinterpret_cast<float4*>(out_meta + o) =
        make_float4((sc * a00 + bb0.x) * pr, (sc * a01 + bb0.y) * pr,
                    (sc * a02 + bb0.z) * pr, (sc * a03 + bb0.w) * pr);
    *reinterpret_cast<float4*>(out_org + o) =
        make_float4((sc * a10 + bb1.x) * pr, (sc * a11 + bb1.y) * pr,
                    (sc * a12 + bb1.z) * pr, (sc * a13 + bb1.w) * pr);
}

// ---------------- line-graph path ----------------
__global__ void k_ef(const int* __restrict__ src, const int* __restrict__ dst,
                     const int* __restrict__ eattr, const int* __restrict__ x,
                     const float* __restrict__ metafeat, const float* __restrict__ atom_emb,
                     const float* __restrict__ bond_emb, const float* __restrict__ meta_W,
                     const float* __restrict__ meta_b, const int* __restrict__ deg_lg,
                     ushort_t* __restrict__ u, int E) {
    __shared__ float W[16 * 128];
    __shared__ float bond[8 * 128];
    __shared__ float mb[128];
    for (int i = threadIdx.x; i < 16 * 128; i += blockDim.x) W[i] = meta_W[i];
    for (int i = threadIdx.x; i < 8 * 128; i += blockDim.x) bond[i] = bond_emb[i];
    if (threadIdx.x < 128) mb[threadIdx.x] = meta_b[threadIdx.x];
    __syncthreads();
    int j = threadIdx.x & 127, li = threadIdx.x >> 7;
    int e = blockIdx.x * 2 + li;
    if (e >= E) return;
    int s = src[e], d = dst[e], at = eattr[e];
    float nsum = atom_emb[(size_t)x[s] * 128 + j] + atom_emb[(size_t)x[d] * 128 + j];
    float msum = 2.f * mb[j];
    const float* ms = metafeat + (size_t)s * 16;
    const float* md = metafeat + (size_t)d * 16;
#pragma unroll
    for (int k = 0; k < 16; k++) msum = fmaf(ms[k] + md[k], W[k * 128 + j], msum);
    float val = bond[at * 128 + j] * nsum * msum;
    float sc = rsqrtf((float)deg_lg[e] + 1.f);
    u[(size_t)e * 128 + j] = f2bf(sc * eluf(val));
}

// v[e] = sc_e*(u[e] + sum u[e']) bf16 -- 64 lanes/edge, unroll-4 prefetch
__global__ void k_lg_v(const int* __restrict__ ptr_lg, const int* __restrict__ adj_lg,
                       const int* __restrict__ deg_lg, const uint_t* __restrict__ u32,
                       uint_t* __restrict__ v32, int E) {
    int l = threadIdx.x & 63, li = threadIdx.x >> 6;
    int e = blockIdx.x * 4 + li;
    if (e >= E) return;
    int p0 = ptr_lg[e], p1 = ptr_lg[e + 1];
    uint_t self = u32[(size_t)e * 64 + l];
    float s0 = bflo(self), s1 = bfhi(self);
    int p = p0;
    for (; p + 4 <= p1; p += 4) {
        int i0 = adj_lg[p], i1 = adj_lg[p + 1], i2 = adj_lg[p + 2], i3 = adj_lg[p + 3];
        uint_t w0 = u32[(size_t)i0 * 64 + l];
        uint_t w1 = u32[(size_t)i1 * 64 + l];
        uint_t w2 = u32[(size_t)i2 * 64 + l];
        uint_t w3 = u32[(size_t)i3 * 64 + l];
        s0 += bflo(w0) + bflo(w1) + bflo(w2) + bflo(w3);
        s1 += bfhi(w0) + bfhi(w1) + bfhi(w2) + bfhi(w3);
    }
    for (; p < p1; p++) {
        uint_t w = u32[(size_t)adj_lg[p] * 64 + l];
        s0 += bflo(w); s1 += bfhi(w);
    }
    float sc = rsqrtf((float)deg_lg[e] + 1.f);
    v32[(size_t)e * 64 + l] = packbf(sc * s0, sc * s1);
}

// g0[n] = sum over incident edges of v[eid] -> bf16 gate buffer
__global__ void k_gate_edges_v(const int* __restrict__ ptr, const int* __restrict__ eid,
                               const uint_t* __restrict__ v32, uint_t* __restrict__ g0,
                               int n) {
    int l = threadIdx.x & 63, li = threadIdx.x >> 6;
    int node = blockIdx.x * 4 + li;
    if (node >= n) return;
    int p0 = ptr[node], p1 = ptr[node + 1];
    float s0 = 0.f, s1 = 0.f;
    int p = p0;
    for (; p + 4 <= p1; p += 4) {
        int i0 = eid[p], i1 = eid[p + 1], i2 = eid[p + 2], i3 = eid[p + 3];
        uint_t w0 = v32[(size_t)i0 * 64 + l];
        uint_t w1 = v32[(size_t)i1 * 64 + l];
        uint_t w2 = v32[(size_t)i2 * 64 + l];
        uint_t w3 = v32[(size_t)i3 * 64 + l];
        s0 += bflo(w0) + bflo(w1) + bflo(w2) + bflo(w3);
        s1 += bfhi(w0) + bfhi(w1) + bfhi(w2) + bfhi(w3);
    }
    for (; p < p1; p++) {
        uint_t w = v32[(size_t)eid[p] * 64 + l];
        s0 += bflo(w); s1 += bfhi(w);
    }
    g0[(size_t)node * 64 + l] = packbf(s0, s1);
}

// fallback: fp32 atomic scatter into g0f (if workspace too small for v)
__global__ void k_lg_scatter(const int* __restrict__ ptr_lg, const int* __restrict__ adj_lg,
                             const int* __restrict__ deg_lg, const ushort_t* __restrict__ u,
                             const int* __restrict__ src, const int* __restrict__ dst,
                             float* __restrict__ g0, int E) {
    int j = threadIdx.x & 127, li = threadIdx.x >> 7;
    int e = blockIdx.x * 2 + li;
    if (e >= E) return;
    int p0 = ptr_lg[e], p1 = ptr_lg[e + 1];
    float acc = bf2f(u[(size_t)e * 128 + j]);
    for (int p = p0; p < p1; p++) acc += bf2f(u[(size_t)adj_lg[p] * 128 + j]);
    float v = rsqrtf((float)deg_lg[e] + 1.f) * acc;
    atomicAdd(&g0[(size_t)src[e] * 128 + j], v);
    atomicAdd(&g0[(size_t)dst[e] * 128 + j], v);
}

// ---------------- pagerank: ELL, 4 lanes/node ----------------
__global__ void k_pr_init(const int* __restrict__ deg, float* __restrict__ c,
                          float* __restrict__ invdeg, int n, float invN) {
    int i = blockIdx.x * blockDim.x + threadIdx.x;
    if (i < n) {
        float iv = 1.f / fmaxf((float)deg[i], 1.f);
        invdeg[i] = iv;
        c[i] = invN * iv;
    }
}

__global__ void k_ell_build(const int* __restrict__ ptr, const int* __restrict__ nbr,
                            int* __restrict__ ell, int N) {
    int tid = blockIdx.x * blockDim.x + threadIdx.x;
    int node = tid >> 2, t = tid & 3;
    if (node >= N) return;
    int p0 = ptr[node];
    int dg = ptr[node + 1] - p0;
    if (dg > ELL_CAP) dg = ELL_CAP;
    int stride = N * 4;
    for (int k = 0; 4 * k + t < dg; k++)
        ell[k * stride + tid] = nbr[p0 + 4 * k + t];
}

__global__ void k_pr_ell(const int* __restrict__ ell, const int* __restrict__ ptr,
                         const int* __restrict__ nbr, const float* __restrict__ invdeg,
                         const float* __restrict__ cin, float* __restrict__ cout,
                         int N, float base, float damp) {
    int tid = blockIdx.x * blockDim.x + threadIdx.x;
    int node = tid >> 2, t = tid & 3;
    if (node >= N) return;
    int p0 = ptr[node], p1 = ptr[node + 1];
    int dg = p1 - p0;
    int dgc = dg > ELL_CAP ? ELL_CAP : dg;
    int stride = N * 4;
    float s = 0.f;
    for (int k = 0; 4 * k + t < dgc; k++) s += cin[ell[k * stride + tid]];
    for (int p = p0 + ELL_CAP + t; p < p1; p += 4) s += cin[nbr[p]];
    s += __shfl_xor(s, 1);
    s += __shfl_xor(s, 2);
    if (t == 0) cout[node] = (base + damp * s) * invdeg[node];
}

// ---------------- pooling + heads ----------------
__global__ void k_pool(const float* __restrict__ out_meta, const float* __restrict__ out_org,
                       float* __restrict__ partial, int n) {
    int tid = threadIdx.x;
    const float* basep = (tid < 128) ? out_meta : out_org;
    int dim = tid & 127;
    float acc = 0.f;
    for (int i = blockIdx.x; i < n; i += gridDim.x) acc += basep[(size_t)i * 128 + dim];
    partial[blockIdx.x * 256 + tid] = acc;
}

__global__ void k_final(const float* __restrict__ partial, int nblocks,
                        const float* __restrict__ cat2_W, const float* __restrict__ cat2_b,
                        const float* __restrict__ pred_W, const float* __restrict__ pred_b,
                        float* __restrict__ out) {
    __shared__ float z[256];
    __shared__ float Z[128];
    int tid = threadIdx.x;
    float acc = 0.f;
    for (int p = 0; p < nblocks; p++) acc += partial[p * 256 + tid];
    z[tid] = acc;
    __syncthreads();
    if (tid < 128) {
        float s = cat2_b[tid];
        for (int k = 0; k < 256; k++) s = fmaf(z[k], cat2_W[k * 128 + tid], s);
        Z[tid] = s;
    }
    __syncthreads();
    if (tid < 12) {
        float s = pred_b[tid];
        for (int k = 0; k < 128; k++) s = fmaf(Z[k], pred_W[k * 12 + tid], s);
        out[tid] = s;
    }
}

// ---------------------------------------------------------------------------
extern "C" void kernel_launch(void* const* d_in, const int* in_sizes, int n_in,
                              void* d_out, int out_size, void* d_ws, size_t ws_size,
                              hipStream_t stream) {
    const int* x            = (const int*)d_in[0];
    const float* metafeat   = (const float*)d_in[1];
    const int* edge_attr    = (const int*)d_in[2];
    const int* edge_index   = (const int*)d_in[3];
    const int* lg_edge_index= (const int*)d_in[4];
    const float* atom_emb   = (const float*)d_in[5];
    const float* bond_emb   = (const float*)d_in[6];
    const float* meta_W     = (const float*)d_in[7];
    const float* meta_b     = (const float*)d_in[8];
    const float* org_W      = (const float*)d_in[9];
    const float* org_b      = (const float*)d_in[10];
    const float* org1_W     = (const float*)d_in[11];
    const float* org1_b     = (const float*)d_in[12];
    const float* mconv_W    = (const float*)d_in[13];
    const float* mconv_b    = (const float*)d_in[14];
    const float* mconv1_W   = (const float*)d_in[15];
    const float* mconv1_b   = (const float*)d_in[16];
    const float* lg_W       = (const float*)d_in[17];
    const float* lg_b       = (const float*)d_in[18];
    const float* cat2_W     = (const float*)d_in[21];
    const float* cat2_b     = (const float*)d_in[22];
    const float* pred_W     = (const float*)d_in[23];
    const float* pred_b     = (const float*)d_in[24];

    const int N = in_sizes[0];
    const int E = in_sizes[2];
    const int ELG = in_sizes[4] / 2;
    const int* src = edge_index;
    const int* dst = edge_index + E;
    const int* ls = lg_edge_index;
    const int* ld = lg_edge_index + ELG;

    // ---- workspace carve ----
    char* w = (char*)d_ws;
    auto alloc = [&](size_t bytes) -> void* {
        void* p = (void*)w;
        w += (bytes + 255) & ~(size_t)255;
        return p;
    };
    int* deg_n   = (int*)alloc((size_t)N * 4);
    int* ptr_n   = (int*)alloc((size_t)(N + 1) * 4);
    int* cur_n   = (int*)alloc((size_t)N * 4);
    int* adj_nbr = (int*)alloc((size_t)2 * E * 4);
    int* adj_eid = (int*)alloc((size_t)2 * E * 4);
    int* deg_lg  = (int*)alloc((size_t)E * 4);
    int* ptr_lg  = (int*)alloc((size_t)(E + 1) * 4);
    int* cur_lg  = (int*)alloc((size_t)E * 4);
    int* adj_lg  = (int*)alloc((size_t)2 * ELG * 4);
    int* bsum    = (int*)alloc((size_t)SCAN_NB * 4);
    float* c_a   = (float*)alloc((size_t)N * 4);
    float* c_b   = (float*)alloc((size_t)N * 4);
    float* invdg = (float*)alloc((size_t)N * 4);
    float* partial = (float*)alloc((size_t)POOL_BLOCKS * 256 * 4);
    uint_t* gateA = (uint_t*)alloc((size_t)N * 64 * 4);   // bf16: gate_n then gate_l
    float* g0f   = (float*)alloc((size_t)N * 128 * 4);    // fp32 fallback gate accum
    uint_t* h_orgb  = (uint_t*)alloc((size_t)N * 64 * 4); // bf16
    uint_t* h_metab = (uint_t*)alloc((size_t)N * 64 * 4); // bf16
    size_t nodeB = (size_t)N * 64;                         // uints per bf16 node array
    size_t u_bytes = (size_t)E * 64 * 4;                   // E x 128 bf16
    size_t reg_bytes = 4 * nodeB * 4;
    uint_t* reg = (uint_t*)alloc(reg_bytes > u_bytes ? reg_bytes : u_bytes);
    uint_t* nf0b = reg;
    uint_t* mf0b = reg + nodeB;
    uint_t* m0   = reg + 2 * nodeB;
    uint_t* m1   = reg + 3 * nodeB;
    ushort_t* u  = (ushort_t*)reg;   // overlays nf0b..m1 (dead by then)
    int* ell     = (int*)reg;        // overlays nf0b quarter after u dies
    size_t used = (size_t)(w - (char*)d_ws);
    uint_t* vbuf = nullptr;
    if (ws_size >= used + u_bytes + 1024) vbuf = (uint_t*)alloc(u_bytes);
    (void)n_in; (void)out_size;

    float* out_pred = (float*)d_out;
    float* out_meta = out_pred + 12;
    float* out_org  = out_pred + 12 + (size_t)N * 128;

    // ---- CSR build ----
    hipMemsetAsync(deg_n, 0, (size_t)N * 4, stream);
    hipMemsetAsync(deg_lg, 0, (size_t)E * 4, stream);
    k_count<<<(E + 255) / 256, 256, 0, stream>>>(src, dst, E, deg_n);
    {
        int C = (N + SCAN_NB - 1) / SCAN_NB;
        k_scan1<<<SCAN_NB, 256, 0, stream>>>(deg_n, N, C, bsum);
        k_scan2<<<1, 256, 0, stream>>>(bsum, SCAN_NB, ptr_n + N);
        k_scan3<<<SCAN_NB, 256, 0, stream>>>(deg_n, bsum, N, C, ptr_n, cur_n);
    }
    k_fill<<<(E + 255) / 256, 256, 0, stream>>>(src, dst, E, cur_n, adj_nbr, adj_eid, 2 * E);
    k_count<<<(ELG + 255) / 256, 256, 0, stream>>>(ls, ld, ELG, deg_lg);
    {
        int C = (E + SCAN_NB - 1) / SCAN_NB;
        k_scan1<<<SCAN_NB, 256, 0, stream>>>(deg_lg, E, C, bsum);
        k_scan2<<<1, 256, 0, stream>>>(bsum, SCAN_NB, ptr_lg + E);
        k_scan3<<<SCAN_NB, 256, 0, stream>>>(deg_lg, bsum, E, C, ptr_lg, cur_lg);
    }
    k_fill<<<(ELG + 255) / 256, 256, 0, stream>>>(ls, ld, ELG, cur_lg, adj_lg, nullptr, 2 * ELG);

    // ---- encoders + gate_n (bf16) ----
    k_encoder<<<(N * 64 + 255) / 256, 256, 0, stream>>>(x, metafeat, atom_emb, meta_W, meta_b,
                                                        nf0b, mf0b, N);
    k_gate_node<<<(N + 3) / 4, 256, 0, stream>>>(ptr_n, adj_eid, edge_attr, bond_emb, gateA, N);

    const int gb_n = (N + 127) / 128;

    // ---- GCN layer 1 (bf16 in, bf16 out) ----
    k_gemm<1, 0, 1, 1><<<gb_n, 256, 0, stream>>>(nf0b, gateA, org_W, nullptr, deg_n, m0, N);
    k_gemm<1, 0, 1, 1><<<gb_n, 256, 0, stream>>>(mf0b, gateA, mconv_W, nullptr, deg_n, m1, N);
    k_agg_dual<<<(N + 7) / 8, 256, 0, stream>>>(ptr_n, adj_nbr, m0, m1, org_b, mconv_b,
                                                deg_n, h_orgb, h_metab, N);
    // reg region becomes u (bf16)

    // ---- line-graph path ----
    k_ef<<<(E + 1) / 2, 256, 0, stream>>>(src, dst, edge_attr, x, metafeat, atom_emb,
                                          bond_emb, meta_W, meta_b, deg_lg, u, E);
    if (vbuf) {
        k_lg_v<<<(E + 3) / 4, 256, 0, stream>>>(ptr_lg, adj_lg, deg_lg, (const uint_t*)u,
                                                vbuf, E);
        k_gate_edges_v<<<(N + 3) / 4, 256, 0, stream>>>(ptr_n, adj_eid, vbuf, gateA, N);
        k_gemm<0, 1, 1, 1><<<gb_n, 256, 0, stream>>>(gateA, nullptr, lg_W, lg_b, deg_n,
                                                     gateA, N);  // in-place bf16
    } else {
        hipMemsetAsync(g0f, 0, (size_t)N * 128 * 4, stream);
        k_lg_scatter<<<(E + 1) / 2, 256, 0, stream>>>(ptr_lg, adj_lg, deg_lg, u, src, dst,
                                                      g0f, E);
        k_gemm<0, 1, 0, 1><<<gb_n, 256, 0, stream>>>(g0f, nullptr, lg_W, lg_b, deg_n,
                                                     gateA, N);
    }

    // ---- GCN layer 2 (gated, bf16 in/out) ----
    k_gemm<1, 0, 1, 1><<<gb_n, 256, 0, stream>>>(h_orgb, gateA, org1_W, nullptr, deg_n, m0, N);
    k_gemm<1, 0, 1, 1><<<gb_n, 256, 0, stream>>>(h_metab, gateA, mconv1_W, nullptr, deg_n, m1, N);
    // u dead; nf0b quarter free -> ELL

    // ---- pagerank: ELL build + PR_ITERS graph-captured launches ----
    float invN = (float)(1.0 / (double)N);
    float base = (float)((1.0 - 0.85) / (double)N);
    k_pr_init<<<(N + 255) / 256, 256, 0, stream>>>(deg_n, c_a, invdg, N, invN);
    int prb = (4 * N + 255) / 256;
    k_ell_build<<<prb, 256, 0, stream>>>(ptr_n, adj_nbr, ell, N);
    float* pin = c_a;
    float* pout = c_b;
    for (int it = 0; it < PR_ITERS; ++it) {
        k_pr_ell<<<prb, 256, 0, stream>>>(ell, ptr_n, adj_nbr, invdg, pin, pout, N,
                                          base, 0.85f);
        float* t = pin; pin = pout; pout = t;
    }

    // ---- final agg + pagerank scale -> d_out, pooling, heads ----
    k_agg_hat<<<(N + 7) / 8, 256, 0, stream>>>(ptr_n, adj_nbr, m1, m0, mconv1_b, org1_b,
                                               deg_n, pin, out_meta, out_org, N);
    k_pool<<<POOL_BLOCKS, 256, 0, stream>>>(out_meta, out_org, partial, N);
    k_final<<<1, 256, 0, stream>>>(partial, POOL_BLOCKS, cat2_W, cat2_b, pred_W, pred_b, out_pred);
}

// Round 7
// 2363.757 us; speedup vs baseline: 1.9705x; 1.1574x over previous
//
#include <hip/hip_runtime.h>
#include <hip/hip_bf16.h>
#include <math.h>

// ---------------------------------------------------------------------------
// IMPGNN on MI355X. fp32 accumulate; bf16 storage for streamed/gathered
// intermediates. Tol = 2% of output absmax (measured margin ~7x).
// R7 vs R6:
//   - lg path atomic-free WITHOUT new workspace: v computed in 2 chunks of
//     E/2 edges into d_out-as-scratch (51.2 MB, dead until k_agg_hat), gate
//     accumulated fp32 in g0f via 2 range-filtered node-CSR passes.
//     Removes the 400 MB atomic write-through that kept R6 on the fallback.
//   - m0/m1 interleaved into m01 (uint4 gather per lane in agg kernels).
// ---------------------------------------------------------------------------

#define POOL_BLOCKS 400
#define SCAN_NB 256
#define ELL_CAP 64
#define PR_ITERS 48   // even: result ends in c_a

typedef unsigned short ushort_t;
typedef unsigned int uint_t;

__device__ __forceinline__ float eluf(float x) { return x > 0.f ? x : expm1f(x); }
__device__ __forceinline__ float bf2f(ushort_t v) {
    return __uint_as_float(((unsigned int)v) << 16);
}
__device__ __forceinline__ ushort_t f2bf(float f) {
    unsigned int u = __float_as_uint(f);
    unsigned int lsb = (u >> 16) & 1u;
    u += 0x7fffu + lsb;           // round-to-nearest-even
    return (ushort_t)(u >> 16);
}
__device__ __forceinline__ float bflo(uint_t v) { return __uint_as_float(v << 16); }
__device__ __forceinline__ float bfhi(uint_t v) { return __uint_as_float(v & 0xffff0000u); }
__device__ __forceinline__ uint_t packbf(float a, float b) {
    return (uint_t)f2bf(a) | ((uint_t)f2bf(b) << 16);
}

// ---------------- CSR build ----------------
__global__ void k_count(const int* __restrict__ a, const int* __restrict__ b,
                        int E, int* __restrict__ deg) {
    int e = blockIdx.x * blockDim.x + threadIdx.x;
    if (e < E) { atomicAdd(&deg[a[e]], 1); atomicAdd(&deg[b[e]], 1); }
}

__global__ void k_scan1(const int* __restrict__ deg, int n, int C, int* __restrict__ bsum) {
    __shared__ int red[256];
    int b = blockIdx.x, tid = threadIdx.x;
    int base = b * C, end = min(base + C, n);
    int s = 0;
    for (int i = base + tid; i < end; i += 256) s += deg[i];
    red[tid] = s;
    __syncthreads();
    for (int off = 128; off > 0; off >>= 1) {
        if (tid < off) red[tid] += red[tid + off];
        __syncthreads();
    }
    if (tid == 0) bsum[b] = red[0];
}

__global__ void k_scan2(int* __restrict__ bsum, int NB, int* __restrict__ total_out) {
    __shared__ int s[256];
    int tid = threadIdx.x;
    int v = (tid < NB) ? bsum[tid] : 0;
    s[tid] = v;
    __syncthreads();
    for (int off = 1; off < 256; off <<= 1) {
        int w = (tid >= off) ? s[tid - off] : 0;
        __syncthreads();
        s[tid] += w;
        __syncthreads();
    }
    if (tid < NB) bsum[tid] = s[tid] - v;
    if (tid == 255) *total_out = s[255];
}

__global__ void k_scan3(const int* __restrict__ deg, const int* __restrict__ boff,
                        int n, int C, int* __restrict__ ptr, int* __restrict__ cur) {
    __shared__ int s[256];
    __shared__ int carry;
    int b = blockIdx.x, tid = threadIdx.x;
    int base = b * C, end = min(base + C, n);
    if (tid == 0) carry = boff[b];
    __syncthreads();
    for (int t = base; t < end; t += 256) {
        int i = t + tid;
        int v = (i < end) ? deg[i] : 0;
        s[tid] = v;
        __syncthreads();
        for (int off = 1; off < 256; off <<= 1) {
            int w = (tid >= off) ? s[tid - off] : 0;
            __syncthreads();
            s[tid] += w;
            __syncthreads();
        }
        int p = carry + s[tid] - v;
        if (i < end) { ptr[i] = p; cur[i] = p; }
        __syncthreads();
        if (tid == 0) carry += s[255];
        __syncthreads();
    }
}

__global__ void k_fill(const int* __restrict__ a, const int* __restrict__ b, int E,
                       int* __restrict__ cur, int* __restrict__ nbr,
                       int* __restrict__ eid, int cap) {
    int e = blockIdx.x * blockDim.x + threadIdx.x;
    if (e < E) {
        int s = a[e], d = b[e];
        int p = atomicAdd(&cur[s], 1);
        if (p < cap) { nbr[p] = d; if (eid) eid[p] = e; }
        int q = atomicAdd(&cur[d], 1);
        if (q < cap) { nbr[q] = s; if (eid) eid[q] = e; }
    }
}

// ---------------- encoders (bf16 out) ----------------
__global__ void k_encoder(const int* __restrict__ x, const float* __restrict__ metafeat,
                          const float* __restrict__ atom_emb, const float* __restrict__ meta_W,
                          const float* __restrict__ meta_b, uint_t* __restrict__ nf0,
                          uint_t* __restrict__ mf0, int N) {
    __shared__ float W[16 * 128];
    __shared__ float bsh[128];
    for (int i = threadIdx.x; i < 16 * 128; i += blockDim.x) W[i] = meta_W[i];
    if (threadIdx.x < 128) bsh[threadIdx.x] = meta_b[threadIdx.x];
    __syncthreads();
    int idx = blockIdx.x * blockDim.x + threadIdx.x;
    if (idx < N * 64) {
        int i = idx >> 6, j2 = idx & 63;
        float2 av = *reinterpret_cast<const float2*>(atom_emb + (size_t)x[i] * 128 + j2 * 2);
        nf0[idx] = packbf(av.x, av.y);
        const float* mrow = metafeat + (size_t)i * 16;
        float a0 = bsh[j2 * 2], a1 = bsh[j2 * 2 + 1];
#pragma unroll
        for (int k = 0; k < 16; k++) {
            float m = mrow[k];
            a0 = fmaf(m, W[k * 128 + j2 * 2], a0);
            a1 = fmaf(m, W[k * 128 + j2 * 2 + 1], a1);
        }
        mf0[idx] = packbf(a0, a1);
    }
}

__global__ void k_gate_node(const int* __restrict__ ptr, const int* __restrict__ eid_arr,
                            const int* __restrict__ edge_attr, const float* __restrict__ bond_emb,
                            uint_t* __restrict__ gate, int N) {
    __shared__ float bond[8 * 128];
    for (int i = threadIdx.x; i < 8 * 128; i += blockDim.x) bond[i] = bond_emb[i];
    __syncthreads();
    int l = threadIdx.x & 63, li = threadIdx.x >> 6;
    int node = blockIdx.x * 4 + li;
    if (node >= N) return;
    int p0 = ptr[node], p1 = ptr[node + 1];
    float g0 = 0.f, g1 = 0.f;
    for (int p = p0; p < p1; p++) {
        int a = edge_attr[eid_arr[p]];
        float2 bv = *reinterpret_cast<const float2*>(&bond[a * 128 + l * 2]);
        g0 += bv.x; g1 += bv.y;
    }
    gate[(size_t)node * 64 + l] = packbf(g0, g1);
}

// ---------------- GEMM ----------------
// GATED: A = elu(X*G). IBF16: X packed bf16 pitch 64 (G always bf16 pitch 64).
// EPI 0: out = rsqrt(deg+1)*acc   EPI 1: out = acc + deg*bias
// OBF16: bf16 out. OILV: interleaved m01 layout (pitch 128 uints, slot offset
// baked into out pointer; lane writes uint2 at r*128 + tx*4 and +64).
template <int GATED, int EPI, int IBF16, int OBF16, int OILV>
__global__ __launch_bounds__(256, 4) void k_gemm(
    const void* __restrict__ Xv, const void* __restrict__ Gv,
    const float* __restrict__ W, const float* __restrict__ bias,
    const int* __restrict__ deg, void* __restrict__ outv, int M) {
    __shared__ float As[128][33];
    __shared__ float Bs[32][128];
    int tid = threadIdx.x;
    int tx = tid & 15, ty = tid >> 4;
    int row0 = blockIdx.x * 128;

    float acc[8][8];
#pragma unroll
    for (int i = 0; i < 8; i++)
#pragma unroll
        for (int j = 0; j < 8; j++) acc[i][j] = 0.f;

    for (int h = 0; h < 4; h++) {
#pragma unroll
        for (int p = 0; p < 4; p++) {
            int idx = p * 256 + tid;
            int kk = idx >> 5, cg = idx & 31;
            float4 w = *reinterpret_cast<const float4*>(W + (h * 32 + kk) * 128 + cg * 4);
            *reinterpret_cast<float4*>(&Bs[kk][cg * 4]) = w;
        }
        int kg = tid & 7, rr = tid >> 3;
#pragma unroll
        for (int p = 0; p < 4; p++) {
            int r = p * 32 + rr;
            int grow = row0 + r;
            float4 av;
            if (grow < M) {
                float x0, x1, x2, x3;
                if (IBF16) {
                    const uint_t* Xb = (const uint_t*)Xv;
                    uint2 xu = *reinterpret_cast<const uint2*>(
                        Xb + (size_t)grow * 64 + h * 16 + kg * 2);
                    x0 = bflo(xu.x); x1 = bfhi(xu.x); x2 = bflo(xu.y); x3 = bfhi(xu.y);
                } else {
                    const float* Xf = (const float*)Xv;
                    float4 xv = *reinterpret_cast<const float4*>(
                        Xf + (size_t)grow * 128 + h * 32 + kg * 4);
                    x0 = xv.x; x1 = xv.y; x2 = xv.z; x3 = xv.w;
                }
                if (GATED) {
                    const uint_t* Gb = (const uint_t*)Gv;
                    uint2 gu = *reinterpret_cast<const uint2*>(
                        Gb + (size_t)grow * 64 + h * 16 + kg * 2);
                    av.x = eluf(x0 * bflo(gu.x)); av.y = eluf(x1 * bfhi(gu.x));
                    av.z = eluf(x2 * bflo(gu.y)); av.w = eluf(x3 * bfhi(gu.y));
                } else {
                    av = make_float4(x0, x1, x2, x3);
                }
            } else av = make_float4(0.f, 0.f, 0.f, 0.f);
            As[r][kg * 4 + 0] = av.x; As[r][kg * 4 + 1] = av.y;
            As[r][kg * 4 + 2] = av.z; As[r][kg * 4 + 3] = av.w;
        }
        __syncthreads();
#pragma unroll 8
        for (int k = 0; k < 32; k++) {
            float a[8], b[8];
#pragma unroll
            for (int i = 0; i < 8; i++) a[i] = As[ty * 8 + i][k];
            float4 b0 = *reinterpret_cast<const float4*>(&Bs[k][tx * 4]);
            float4 b1 = *reinterpret_cast<const float4*>(&Bs[k][64 + tx * 4]);
            b[0] = b0.x; b[1] = b0.y; b[2] = b0.z; b[3] = b0.w;
            b[4] = b1.x; b[5] = b1.y; b[6] = b1.z; b[7] = b1.w;
#pragma unroll
            for (int i = 0; i < 8; i++)
#pragma unroll
                for (int j = 0; j < 8; j++) acc[i][j] = fmaf(a[i], b[j], acc[i][j]);
        }
        __syncthreads();
    }
#pragma unroll
    for (int i = 0; i < 8; i++) {
        int r = row0 + ty * 8 + i;
        if (r < M) {
            float o[8];
            if (EPI == 0) {
                float sc = rsqrtf((float)deg[r] + 1.0f);
#pragma unroll
                for (int j = 0; j < 8; j++) o[j] = acc[i][j] * sc;
            } else {
                float dg = (float)deg[r];
                float4 ba = *reinterpret_cast<const float4*>(bias + tx * 4);
                float4 bb = *reinterpret_cast<const float4*>(bias + 64 + tx * 4);
                o[0] = acc[i][0] + dg * ba.x; o[1] = acc[i][1] + dg * ba.y;
                o[2] = acc[i][2] + dg * ba.z; o[3] = acc[i][3] + dg * ba.w;
                o[4] = acc[i][4] + dg * bb.x; o[5] = acc[i][5] + dg * bb.y;
                o[6] = acc[i][6] + dg * bb.z; o[7] = acc[i][7] + dg * bb.w;
            }
            if (OBF16) {
                uint_t* ob = (uint_t*)outv;
                uint2 q0, q1;
                q0.x = packbf(o[0], o[1]); q0.y = packbf(o[2], o[3]);
                q1.x = packbf(o[4], o[5]); q1.y = packbf(o[6], o[7]);
                if (OILV) {
                    *reinterpret_cast<uint2*>(ob + (size_t)r * 128 + tx * 4) = q0;
                    *reinterpret_cast<uint2*>(ob + (size_t)r * 128 + 64 + tx * 4) = q1;
                } else {
                    *reinterpret_cast<uint2*>(ob + (size_t)r * 64 + tx * 2) = q0;
                    *reinterpret_cast<uint2*>(ob + (size_t)r * 64 + 32 + tx * 2) = q1;
                }
            } else {
                float* out = (float*)outv;
                *reinterpret_cast<float4*>(out + (size_t)r * 128 + tx * 4) =
                    make_float4(o[0], o[1], o[2], o[3]);
                *reinterpret_cast<float4*>(out + (size_t)r * 128 + 64 + tx * 4) =
                    make_float4(o[4], o[5], o[6], o[7]);
            }
        }
    }
}

// ---------------- node aggregations on interleaved m01 ----------------
// m01 layout: uint4 at [node*128 + c*4]: .xy = m0 dims 4c..4c+3, .zw = m1 same.
__global__ void k_agg_dual(const int* __restrict__ ptr, const int* __restrict__ nbr,
                           const uint_t* __restrict__ m01,
                           const float* __restrict__ b0, const float* __restrict__ b1,
                           const int* __restrict__ deg, uint_t* __restrict__ h0,
                           uint_t* __restrict__ h1, int n) {
    int c = threadIdx.x & 31, li = threadIdx.x >> 5;
    int node = blockIdx.x * 8 + li;
    if (node >= n) return;
    int p0 = ptr[node], p1 = ptr[node + 1];
    uint4 s = *reinterpret_cast<const uint4*>(m01 + (size_t)node * 128 + c * 4);
    float a00 = bflo(s.x), a01 = bfhi(s.x), a02 = bflo(s.y), a03 = bfhi(s.y);
    float a10 = bflo(s.z), a11 = bfhi(s.z), a12 = bflo(s.w), a13 = bfhi(s.w);
    int p = p0;
    for (; p + 4 <= p1; p += 4) {
        int i0 = nbr[p], i1 = nbr[p + 1], i2 = nbr[p + 2], i3 = nbr[p + 3];
        uint4 v0 = *reinterpret_cast<const uint4*>(m01 + (size_t)i0 * 128 + c * 4);
        uint4 v1 = *reinterpret_cast<const uint4*>(m01 + (size_t)i1 * 128 + c * 4);
        uint4 v2 = *reinterpret_cast<const uint4*>(m01 + (size_t)i2 * 128 + c * 4);
        uint4 v3 = *reinterpret_cast<const uint4*>(m01 + (size_t)i3 * 128 + c * 4);
        a00 += bflo(v0.x) + bflo(v1.x) + bflo(v2.x) + bflo(v3.x);
        a01 += bfhi(v0.x) + bfhi(v1.x) + bfhi(v2.x) + bfhi(v3.x);
        a02 += bflo(v0.y) + bflo(v1.y) + bflo(v2.y) + bflo(v3.y);
        a03 += bfhi(v0.y) + bfhi(v1.y) + bfhi(v2.y) + bfhi(v3.y);
        a10 += bflo(v0.z) + bflo(v1.z) + bflo(v2.z) + bflo(v3.z);
        a11 += bfhi(v0.z) + bfhi(v1.z) + bfhi(v2.z) + bfhi(v3.z);
        a12 += bflo(v0.w) + bflo(v1.w) + bflo(v2.w) + bflo(v3.w);
        a13 += bfhi(v0.w) + bfhi(v1.w) + bfhi(v2.w) + bfhi(v3.w);
    }
    for (; p < p1; p++) {
        uint4 v = *reinterpret_cast<const uint4*>(m01 + (size_t)nbr[p] * 128 + c * 4);
        a00 += bflo(v.x); a01 += bfhi(v.x); a02 += bflo(v.y); a03 += bfhi(v.y);
        a10 += bflo(v.z); a11 += bfhi(v.z); a12 += bflo(v.w); a13 += bfhi(v.w);
    }
    float sc = rsqrtf((float)deg[node] + 1.f);
    float4 bb0 = *reinterpret_cast<const float4*>(b0 + c * 4);
    float4 bb1 = *reinterpret_cast<const float4*>(b1 + c * 4);
    uint2 o0, o1;
    o0.x = packbf(sc * a00 + bb0.x, sc * a01 + bb0.y);
    o0.y = packbf(sc * a02 + bb0.z, sc * a03 + bb0.w);
    o1.x = packbf(sc * a10 + bb1.x, sc * a11 + bb1.y);
    o1.y = packbf(sc * a12 + bb1.z, sc * a13 + bb1.w);
    size_t idx = (size_t)node * 64 + c * 2;
    *reinterpret_cast<uint2*>(h0 + idx) = o0;
    *reinterpret_cast<uint2*>(h1 + idx) = o1;
}

// final agg: m01 slot0 = org (out_org), slot1 = meta (out_meta), + pr scale
__global__ void k_agg_hat(const int* __restrict__ ptr, const int* __restrict__ nbr,
                          const uint_t* __restrict__ m01,
                          const float* __restrict__ b_org, const float* __restrict__ b_meta,
                          const int* __restrict__ deg, const float* __restrict__ c_pr,
                          float* __restrict__ out_meta, float* __restrict__ out_org, int n) {
    int c = threadIdx.x & 31, li = threadIdx.x >> 5;
    int node = blockIdx.x * 8 + li;
    if (node >= n) return;
    int p0 = ptr[node], p1 = ptr[node + 1];
    uint4 s = *reinterpret_cast<const uint4*>(m01 + (size_t)node * 128 + c * 4);
    float a00 = bflo(s.x), a01 = bfhi(s.x), a02 = bflo(s.y), a03 = bfhi(s.y);
    float a10 = bflo(s.z), a11 = bfhi(s.z), a12 = bflo(s.w), a13 = bfhi(s.w);
    int p = p0;
    for (; p + 4 <= p1; p += 4) {
        int i0 = nbr[p], i1 = nbr[p + 1], i2 = nbr[p + 2], i3 = nbr[p + 3];
        uint4 v0 = *reinterpret_cast<const uint4*>(m01 + (size_t)i0 * 128 + c * 4);
        uint4 v1 = *reinterpret_cast<const uint4*>(m01 + (size_t)i1 * 128 + c * 4);
        uint4 v2 = *reinterpret_cast<const uint4*>(m01 + (size_t)i2 * 128 + c * 4);
        uint4 v3 = *reinterpret_cast<const uint4*>(m01 + (size_t)i3 * 128 + c * 4);
        a00 += bflo(v0.x) + bflo(v1.x) + bflo(v2.x) + bflo(v3.x);
        a01 += bfhi(v0.x) + bfhi(v1.x) + bfhi(v2.x) + bfhi(v3.x);
        a02 += bflo(v0.y) + bflo(v1.y) + bflo(v2.y) + bflo(v3.y);
        a03 += bfhi(v0.y) + bfhi(v1.y) + bfhi(v2.y) + bfhi(v3.y);
        a10 += bflo(v0.z) + bflo(v1.z) + bflo(v2.z) + bflo(v3.z);
        a11 += bfhi(v0.z) + bfhi(v1.z) + bfhi(v2.z) + bfhi(v3.z);
        a12 += bflo(v0.w) + bflo(v1.w) + bflo(v2.w) + bflo(v3.w);
        a13 += bfhi(v0.w) + bfhi(v1.w) + bfhi(v2.w) + bfhi(v3.w);
    }
    for (; p < p1; p++) {
        uint4 v = *reinterpret_cast<const uint4*>(m01 + (size_t)nbr[p] * 128 + c * 4);
        a00 += bflo(v.x); a01 += bfhi(v.x); a02 += bflo(v.y); a03 += bfhi(v.y);
        a10 += bflo(v.z); a11 += bfhi(v.z); a12 += bflo(v.w); a13 += bfhi(v.w);
    }
    int dg = deg[node];
    float sc = rsqrtf((float)dg + 1.f);
    float pr = c_pr[node] * fmaxf((float)dg, 1.f);
    float4 bo = *reinterpret_cast<const float4*>(b_org + c * 4);
    float4 bm = *reinterpret_cast<const float4*>(b_meta + c * 4);
    size_t o = (size_t)node * 128 + c * 4;
    *reinterpret_cast<float4*>(out_org + o) =
        make_float4((sc * a00 + bo.x) * pr, (sc * a01 + bo.y) * pr,
                    (sc * a02 + bo.z) * pr, (sc * a03 + bo.w) * pr);
    *reinterpret_cast<float4*>(out_meta + o) =
        make_float4((sc * a10 + bm.x) * pr, (sc * a11 + bm.y) * pr,
                    (sc * a12 + bm.z) * pr, (sc * a13 + bm.w) * pr);
}

// ---------------- line-graph path ----------------
__global__ void k_ef(const int* __restrict__ src, const int* __restrict__ dst,
                     const int* __restrict__ eattr, const int* __restrict__ x,
                     const float* __restrict__ metafeat, const float* __restrict__ atom_emb,
                     const float* __restrict__ bond_emb, const float* __restrict__ meta_W,
                     const float* __restrict__ meta_b, const int* __restrict__ deg_lg,
                     ushort_t* __restrict__ u, int E) {
    __shared__ float W[16 * 128];
    __shared__ float bond[8 * 128];
    __shared__ float mb[128];
    for (int i = threadIdx.x; i < 16 * 128; i += blockDim.x) W[i] = meta_W[i];
    for (int i = threadIdx.x; i < 8 * 128; i += blockDim.x) bond[i] = bond_emb[i];
    if (threadIdx.x < 128) mb[threadIdx.x] = meta_b[threadIdx.x];
    __syncthreads();
    int j = threadIdx.x & 127, li = threadIdx.x >> 7;
    int e = blockIdx.x * 2 + li;
    if (e >= E) return;
    int s = src[e], d = dst[e], at = eattr[e];
    float nsum = atom_emb[(size_t)x[s] * 128 + j] + atom_emb[(size_t)x[d] * 128 + j];
    float msum = 2.f * mb[j];
    const float* ms = metafeat + (size_t)s * 16;
    const float* md = metafeat + (size_t)d * 16;
#pragma unroll
    for (int k = 0; k < 16; k++) msum = fmaf(ms[k] + md[k], W[k * 128 + j], msum);
    float val = bond[at * 128 + j] * nsum * msum;
    float sc = rsqrtf((float)deg_lg[e] + 1.f);
    u[(size_t)e * 128 + j] = f2bf(sc * eluf(val));
}

// v[e] = sc_e*(u[e] + sum u[e']) bf16, chunk [e0,e1) -> vout (row e-e0)
__global__ void k_lg_v(const int* __restrict__ ptr_lg, const int* __restrict__ adj_lg,
                       const int* __restrict__ deg_lg, const uint_t* __restrict__ u32,
                       uint_t* __restrict__ vout, int e0, int e1) {
    int l = threadIdx.x & 63, li = threadIdx.x >> 6;
    int e = e0 + blockIdx.x * 4 + li;
    if (e >= e1) return;
    int p0 = ptr_lg[e], p1 = ptr_lg[e + 1];
    uint_t self = u32[(size_t)e * 64 + l];
    float s0 = bflo(self), s1 = bfhi(self);
    int p = p0;
    for (; p + 4 <= p1; p += 4) {
        int i0 = adj_lg[p], i1 = adj_lg[p + 1], i2 = adj_lg[p + 2], i3 = adj_lg[p + 3];
        uint_t w0 = u32[(size_t)i0 * 64 + l];
        uint_t w1 = u32[(size_t)i1 * 64 + l];
        uint_t w2 = u32[(size_t)i2 * 64 + l];
        uint_t w3 = u32[(size_t)i3 * 64 + l];
        s0 += bflo(w0) + bflo(w1) + bflo(w2) + bflo(w3);
        s1 += bfhi(w0) + bfhi(w1) + bfhi(w2) + bfhi(w3);
    }
    for (; p < p1; p++) {
        uint_t w = u32[(size_t)adj_lg[p] * 64 + l];
        s0 += bflo(w); s1 += bfhi(w);
    }
    float sc = rsqrtf((float)deg_lg[e] + 1.f);
    vout[(size_t)(e - e0) * 64 + l] = packbf(sc * s0, sc * s1);
}

// g0f[n] (+)= sum over incident eids in [e0,e1) of v[eid-e0]; wave-uniform branch
template <int FIRST>
__global__ void k_gate_pass(const int* __restrict__ ptr, const int* __restrict__ eid,
                            const uint_t* __restrict__ v32, float* __restrict__ g0f,
                            int n, int e0, int e1) {
    int l = threadIdx.x & 63, li = threadIdx.x >> 6;
    int node = blockIdx.x * 4 + li;
    if (node >= n) return;
    int p0 = ptr[node], p1 = ptr[node + 1];
    float s0 = 0.f, s1 = 0.f;
    for (int p = p0; p < p1; p++) {
        int e = eid[p];
        if (e >= e0 && e < e1) {
            uint_t w = v32[(size_t)(e - e0) * 64 + l];
            s0 += bflo(w); s1 += bfhi(w);
        }
    }
    float2* out = reinterpret_cast<float2*>(g0f + (size_t)node * 128 + l * 2);
    if (FIRST) {
        *out = make_float2(s0, s1);
    } else {
        float2 c = *out;
        *out = make_float2(c.x + s0, c.y + s1);
    }
}

// ---------------- pagerank: ELL, 4 lanes/node ----------------
__global__ void k_pr_init(const int* __restrict__ deg, float* __restrict__ c,
                          float* __restrict__ invdeg, int n, float invN) {
    int i = blockIdx.x * blockDim.x + threadIdx.x;
    if (i < n) {
        float iv = 1.f / fmaxf((float)deg[i], 1.f);
        invdeg[i] = iv;
        c[i] = invN * iv;
    }
}

__global__ void k_ell_build(const int* __restrict__ ptr, const int* __restrict__ nbr,
                            int* __restrict__ ell, int N) {
    int tid = blockIdx.x * blockDim.x + threadIdx.x;
    int node = tid >> 2, t = tid & 3;
    if (node >= N) return;
    int p0 = ptr[node];
    int dg = ptr[node + 1] - p0;
    if (dg > ELL_CAP) dg = ELL_CAP;
    int stride = N * 4;
    for (int k = 0; 4 * k + t < dg; k++)
        ell[k * stride + tid] = nbr[p0 + 4 * k + t];
}

__global__ void k_pr_ell(const int* __restrict__ ell, const int* __restrict__ ptr,
                         const int* __restrict__ nbr, const float* __restrict__ invdeg,
                         const float* __restrict__ cin, float* __restrict__ cout,
                         int N, float base, float damp) {
    int tid = blockIdx.x * blockDim.x + threadIdx.x;
    int node = tid >> 2, t = tid & 3;
    if (node >= N) return;
    int p0 = ptr[node], p1 = ptr[node + 1];
    int dg = p1 - p0;
    int dgc = dg > ELL_CAP ? ELL_CAP : dg;
    int stride = N * 4;
    float s = 0.f;
    for (int k = 0; 4 * k + t < dgc; k++) s += cin[ell[k * stride + tid]];
    for (int p = p0 + ELL_CAP + t; p < p1; p += 4) s += cin[nbr[p]];
    s += __shfl_xor(s, 1);
    s += __shfl_xor(s, 2);
    if (t == 0) cout[node] = (base + damp * s) * invdeg[node];
}

// ---------------- pooling + heads ----------------
__global__ void k_pool(const float* __restrict__ out_meta, const float* __restrict__ out_org,
                       float* __restrict__ partial, int n) {
    int tid = threadIdx.x;
    const float* basep = (tid < 128) ? out_meta : out_org;
    int dim = tid & 127;
    float acc = 0.f;
    for (int i = blockIdx.x; i < n; i += gridDim.x) acc += basep[(size_t)i * 128 + dim];
    partial[blockIdx.x * 256 + tid] = acc;
}

__global__ void k_final(const float* __restrict__ partial, int nblocks,
                        const float* __restrict__ cat2_W, const float* __restrict__ cat2_b,
                        const float* __restrict__ pred_W, const float* __restrict__ pred_b,
                        float* __restrict__ out) {
    __shared__ float z[256];
    __shared__ float Z[128];
    int tid = threadIdx.x;
    float acc = 0.f;
    for (int p = 0; p < nblocks; p++) acc += partial[p * 256 + tid];
    z[tid] = acc;
    __syncthreads();
    if (tid < 128) {
        float s = cat2_b[tid];
        for (int k = 0; k < 256; k++) s = fmaf(z[k], cat2_W[k * 128 + tid], s);
        Z[tid] = s;
    }
    __syncthreads();
    if (tid < 12) {
        float s = pred_b[tid];
        for (int k = 0; k < 128; k++) s = fmaf(Z[k], pred_W[k * 12 + tid], s);
        out[tid] = s;
    }
}

// ---------------------------------------------------------------------------
extern "C" void kernel_launch(void* const* d_in, const int* in_sizes, int n_in,
                              void* d_out, int out_size, void* d_ws, size_t ws_size,
                              hipStream_t stream) {
    const int* x            = (const int*)d_in[0];
    const float* metafeat   = (const float*)d_in[1];
    const int* edge_attr    = (const int*)d_in[2];
    const int* edge_index   = (const int*)d_in[3];
    const int* lg_edge_index= (const int*)d_in[4];
    const float* atom_emb   = (const float*)d_in[5];
    const float* bond_emb   = (const float*)d_in[6];
    const float* meta_W     = (const float*)d_in[7];
    const float* meta_b     = (const float*)d_in[8];
    const float* org_W      = (const float*)d_in[9];
    const float* org_b      = (const float*)d_in[10];
    const float* org1_W     = (const float*)d_in[11];
    const float* org1_b     = (const float*)d_in[12];
    const float* mconv_W    = (const float*)d_in[13];
    const float* mconv_b    = (const float*)d_in[14];
    const float* mconv1_W   = (const float*)d_in[15];
    const float* mconv1_b   = (const float*)d_in[16];
    const float* lg_W       = (const float*)d_in[17];
    const float* lg_b       = (const float*)d_in[18];
    const float* cat2_W     = (const float*)d_in[21];
    const float* cat2_b     = (const float*)d_in[22];
    const float* pred_W     = (const float*)d_in[23];
    const float* pred_b     = (const float*)d_in[24];

    const int N = in_sizes[0];
    const int E = in_sizes[2];
    const int ELG = in_sizes[4] / 2;
    const int* src = edge_index;
    const int* dst = edge_index + E;
    const int* ls = lg_edge_index;
    const int* ld = lg_edge_index + ELG;

    // ---- workspace carve (~193 MB, proven R6 footprint) ----
    char* w = (char*)d_ws;
    auto alloc = [&](size_t bytes) -> void* {
        void* p = (void*)w;
        w += (bytes + 255) & ~(size_t)255;
        return p;
    };
    int* deg_n   = (int*)alloc((size_t)N * 4);
    int* ptr_n   = (int*)alloc((size_t)(N + 1) * 4);
    int* cur_n   = (int*)alloc((size_t)N * 4);
    int* adj_nbr = (int*)alloc((size_t)2 * E * 4);
    int* adj_eid = (int*)alloc((size_t)2 * E * 4);
    int* deg_lg  = (int*)alloc((size_t)E * 4);
    int* ptr_lg  = (int*)alloc((size_t)(E + 1) * 4);
    int* cur_lg  = (int*)alloc((size_t)E * 4);
    int* adj_lg  = (int*)alloc((size_t)2 * ELG * 4);
    int* bsum    = (int*)alloc((size_t)SCAN_NB * 4);
    float* c_a   = (float*)alloc((size_t)N * 4);
    float* c_b   = (float*)alloc((size_t)N * 4);
    float* invdg = (float*)alloc((size_t)N * 4);
    float* partial = (float*)alloc((size_t)POOL_BLOCKS * 256 * 4);
    uint_t* gateA = (uint_t*)alloc((size_t)N * 64 * 4);   // bf16: gate_n then gate_l
    float* g0f   = (float*)alloc((size_t)N * 128 * 4);    // fp32 gate accumulator
    uint_t* h_orgb  = (uint_t*)alloc((size_t)N * 64 * 4); // bf16
    uint_t* h_metab = (uint_t*)alloc((size_t)N * 64 * 4); // bf16
    size_t nodeB = (size_t)N * 64;                         // uints per bf16 node array
    size_t u_bytes = (size_t)E * 64 * 4;                   // E x 128 bf16
    size_t reg_bytes = 4 * nodeB * 4;
    uint_t* reg = (uint_t*)alloc(reg_bytes > u_bytes ? reg_bytes : u_bytes);
    uint_t* nf0b = reg;
    uint_t* mf0b = reg + nodeB;
    uint_t* m01  = reg + 2 * nodeB;  // interleaved m0/m1, pitch 128 uints/node
    ushort_t* u  = (ushort_t*)reg;   // overlays nf0b..m01 (all dead by then)
    int* ell     = (int*)reg;        // overlays nf0b quarter after u dies
    (void)n_in; (void)ws_size;

    float* out_pred = (float*)d_out;
    float* out_meta = out_pred + 12;
    float* out_org  = out_pred + 12 + (size_t)N * 128;
    // d_out doubles as the v-chunk scratch during the lg path (dead until agg_hat)
    uint_t* vhalf = (uint_t*)d_out;   // capacity: out_size*4 >= (E/2)*256 bytes
    (void)out_size;

    // ---- CSR build ----
    hipMemsetAsync(deg_n, 0, (size_t)N * 4, stream);
    hipMemsetAsync(deg_lg, 0, (size_t)E * 4, stream);
    k_count<<<(E + 255) / 256, 256, 0, stream>>>(src, dst, E, deg_n);
    {
        int C = (N + SCAN_NB - 1) / SCAN_NB;
        k_scan1<<<SCAN_NB, 256, 0, stream>>>(deg_n, N, C, bsum);
        k_scan2<<<1, 256, 0, stream>>>(bsum, SCAN_NB, ptr_n + N);
        k_scan3<<<SCAN_NB, 256, 0, stream>>>(deg_n, bsum, N, C, ptr_n, cur_n);
    }
    k_fill<<<(E + 255) / 256, 256, 0, stream>>>(src, dst, E, cur_n, adj_nbr, adj_eid, 2 * E);
    k_count<<<(ELG + 255) / 256, 256, 0, stream>>>(ls, ld, ELG, deg_lg);
    {
        int C = (E + SCAN_NB - 1) / SCAN_NB;
        k_scan1<<<SCAN_NB, 256, 0, stream>>>(deg_lg, E, C, bsum);
        k_scan2<<<1, 256, 0, stream>>>(bsum, SCAN_NB, ptr_lg + E);
        k_scan3<<<SCAN_NB, 256, 0, stream>>>(deg_lg, bsum, E, C, ptr_lg, cur_lg);
    }
    k_fill<<<(ELG + 255) / 256, 256, 0, stream>>>(ls, ld, ELG, cur_lg, adj_lg, nullptr, 2 * ELG);

    // ---- encoders + gate_n (bf16) ----
    k_encoder<<<(N * 64 + 255) / 256, 256, 0, stream>>>(x, metafeat, atom_emb, meta_W, meta_b,
                                                        nf0b, mf0b, N);
    k_gate_node<<<(N + 3) / 4, 256, 0, stream>>>(ptr_n, adj_eid, edge_attr, bond_emb, gateA, N);

    const int gb_n = (N + 127) / 128;

    // ---- GCN layer 1 (bf16 in, interleaved bf16 out) ----
    k_gemm<1, 0, 1, 1, 1><<<gb_n, 256, 0, stream>>>(nf0b, gateA, org_W, nullptr, deg_n,
                                                    m01 + 0, N);   // slot 0 = org
    k_gemm<1, 0, 1, 1, 1><<<gb_n, 256, 0, stream>>>(mf0b, gateA, mconv_W, nullptr, deg_n,
                                                    m01 + 2, N);   // slot 1 = meta
    k_agg_dual<<<(N + 7) / 8, 256, 0, stream>>>(ptr_n, adj_nbr, m01, org_b, mconv_b,
                                                deg_n, h_orgb, h_metab, N);
    // reg region becomes u (bf16)

    // ---- line-graph path: u -> v (2 chunks via d_out scratch) -> g0f fp32 ----
    k_ef<<<(E + 1) / 2, 256, 0, stream>>>(src, dst, edge_attr, x, metafeat, atom_emb,
                                          bond_emb, meta_W, meta_b, deg_lg, u, E);
    {
        int eh = (E + 1) / 2;
        k_lg_v<<<(eh + 3) / 4, 256, 0, stream>>>(ptr_lg, adj_lg, deg_lg, (const uint_t*)u,
                                                 vhalf, 0, eh);
        k_gate_pass<1><<<(N + 3) / 4, 256, 0, stream>>>(ptr_n, adj_eid, vhalf, g0f, N, 0, eh);
        k_lg_v<<<(E - eh + 3) / 4, 256, 0, stream>>>(ptr_lg, adj_lg, deg_lg, (const uint_t*)u,
                                                     vhalf, eh, E);
        k_gate_pass<0><<<(N + 3) / 4, 256, 0, stream>>>(ptr_n, adj_eid, vhalf, g0f, N, eh, E);
    }
    k_gemm<0, 1, 0, 1, 0><<<gb_n, 256, 0, stream>>>(g0f, nullptr, lg_W, lg_b, deg_n,
                                                    gateA, N);   // gate_l bf16

    // ---- GCN layer 2 (gated, bf16 in, interleaved out) ----
    k_gemm<1, 0, 1, 1, 1><<<gb_n, 256, 0, stream>>>(h_orgb, gateA, org1_W, nullptr, deg_n,
                                                    m01 + 0, N);
    k_gemm<1, 0, 1, 1, 1><<<gb_n, 256, 0, stream>>>(h_metab, gateA, mconv1_W, nullptr, deg_n,
                                                    m01 + 2, N);
    // u dead; nf0b quarter free -> ELL

    // ---- pagerank: ELL build + PR_ITERS graph-captured launches ----
    float invN = (float)(1.0 / (double)N);
    float base = (float)((1.0 - 0.85) / (double)N);
    k_pr_init<<<(N + 255) / 256, 256, 0, stream>>>(deg_n, c_a, invdg, N, invN);
    int prb = (4 * N + 255) / 256;
    k_ell_build<<<prb, 256, 0, stream>>>(ptr_n, adj_nbr, ell, N);
    float* pin = c_a;
    float* pout = c_b;
    for (int it = 0; it < PR_ITERS; ++it) {
        k_pr_ell<<<prb, 256, 0, stream>>>(ell, ptr_n, adj_nbr, invdg, pin, pout, N,
                                          base, 0.85f);
        float* t = pin; pin = pout; pout = t;
    }

    // ---- final agg + pagerank scale -> d_out (vhalf scratch now dead) ----
    k_agg_hat<<<(N + 7) / 8, 256, 0, stream>>>(ptr_n, adj_nbr, m01, org1_b, mconv1_b,
                                               deg_n, pin, out_meta, out_org, N);
    k_pool<<<POOL_BLOCKS, 256, 0, stream>>>(out_meta, out_org, partial, N);
    k_final<<<1, 256, 0, stream>>>(partial, POOL_BLOCKS, cat2_W, cat2_b, pred_W, pred_b, out_pred);
}